// Round 6
// baseline (413.707 us; speedup 1.0000x reference)
//
#include <hip/hip_runtime.h>
#include <math.h>

// Problem constants (B=2, Hs=Ws=48, D=768, heads=6, P=4)
#define BB 2
#define NN 12096     // 21 * (48*48/4)
#define LL 2304      // 48*48
#define DD 768
#define HID 192
#define HS 48
#define WS 48

typedef unsigned short u16;
typedef unsigned int u32;
typedef __attribute__((ext_vector_type(8))) __bf16 bf16x8;
typedef __attribute__((ext_vector_type(4))) float f32x4;

__device__ __forceinline__ u16 f2bf(float f) {
  u32 x = __builtin_bit_cast(u32, f);
  u32 r = (x + 0x7fffu + ((x >> 16) & 1u)) >> 16;  // RNE
  return (u16)r;
}
__device__ __forceinline__ float bf2f(u16 u) {
  u32 x = ((u32)u) << 16;
  return __builtin_bit_cast(float, x);
}

template <int N>
__device__ __forceinline__ void waitcnt_vm() {
  if constexpr (N == 0)       asm volatile("s_waitcnt vmcnt(0)" ::: "memory");
  else if constexpr (N == 2)  asm volatile("s_waitcnt vmcnt(2)" ::: "memory");
  else if constexpr (N == 4)  asm volatile("s_waitcnt vmcnt(4)" ::: "memory");
  else if constexpr (N == 6)  asm volatile("s_waitcnt vmcnt(6)" ::: "memory");
  else if constexpr (N == 8)  asm volatile("s_waitcnt vmcnt(8)" ::: "memory");
  else                        asm volatile("s_waitcnt vmcnt(12)" ::: "memory");
}

// ---------------- LayerNorm body (192 threads x 4 contiguous channels) ----------------
template <typename T>
__device__ __forceinline__ void ln_row4(const T* xr, const float* g, const float* bta, u16* yr, int t) {
  float v0, v1, v2, v3;
  if constexpr (sizeof(T) == 2) {
    ushort4 u = *(const ushort4*)(xr + 4 * t);
    v0 = bf2f(u.x); v1 = bf2f(u.y); v2 = bf2f(u.z); v3 = bf2f(u.w);
  } else {
    float4 f = *(const float4*)(xr + 4 * t);
    v0 = f.x; v1 = f.y; v2 = f.z; v3 = f.w;
  }
  float s = v0 + v1 + v2 + v3;
  float s2 = v0 * v0 + v1 * v1 + v2 * v2 + v3 * v3;
#pragma unroll
  for (int off = 32; off; off >>= 1) {
    s += __shfl_down(s, off, 64);
    s2 += __shfl_down(s2, off, 64);
  }
  __shared__ float red[6];
  __shared__ float mv[2];
  int wave = t >> 6, lane = t & 63;
  if (lane == 0) { red[wave] = s; red[3 + wave] = s2; }
  __syncthreads();
  if (t == 0) {
    float ts = red[0] + red[1] + red[2];
    float ts2 = red[3] + red[4] + red[5];
    float m = ts * (1.f / DD);
    float var = ts2 * (1.f / DD) - m * m;
    mv[0] = m;
    mv[1] = rsqrtf(var + 1e-6f);
  }
  __syncthreads();
  float m = mv[0], rs = mv[1];
  float4 gv = *(const float4*)(g + 4 * t);
  float4 bv = *(const float4*)(bta + 4 * t);
  ushort4 o;
  o.x = f2bf((v0 - m) * rs * gv.x + bv.x);
  o.y = f2bf((v1 - m) * rs * gv.y + bv.y);
  o.z = f2bf((v2 - m) * rs * gv.z + bv.z);
  o.w = f2bf((v3 - m) * rs * gv.w + bv.w);
  *(ushort4*)(yr + 4 * t) = o;
}

template <typename T>
__global__ __launch_bounds__(192) void ln_kernel(const T* __restrict__ x,
                                                 const float* __restrict__ g,
                                                 const float* __restrict__ bta,
                                                 u16* __restrict__ y) {
  size_t row = blockIdx.x;
  ln_row4<T>(x + row * DD, g, bta, y + row * DD, threadIdx.x);
}

// merged LN for query (Mq rows) and feat (Mf rows), both fp32
__global__ __launch_bounds__(192) void ln_dual_kernel(const float* __restrict__ xq,
                                                      const float* __restrict__ gq,
                                                      const float* __restrict__ bq,
                                                      u16* __restrict__ yq,
                                                      const float* __restrict__ xf,
                                                      const float* __restrict__ gf,
                                                      const float* __restrict__ bf_,
                                                      u16* __restrict__ yf,
                                                      int Mq) {
  size_t row = blockIdx.x;
  if (row < (size_t)Mq)
    ln_row4<float>(xq + row * DD, gq, bq, yq + row * DD, threadIdx.x);
  else {
    size_t r = row - Mq;
    ln_row4<float>(xf + r * DD, gf, bf_, yf + r * DD, threadIdx.x);
  }
}

// ---------------- bf16 MFMA GEMM ----------------
// C(MxN) = A(MxK)bf16 @ Bt(NxK)bf16 + bias (+res).
// RES: 0 none, 1 fp32, 2 bf16. OUT: 0 fp32, 1 bf16.
// NTSW: 0 -> plain 2D grid; else 1D grid with XCD-aware swizzle (NTSW = n-tile count).
// DBUF: 1 -> double-buffered LDS with COUNTED vmcnt (wait only current tile's loads;
// next tile keeps streaming through compute + barrier). History:
//  - r0/r3: single-buf 128x128, 2 blk/CU, 2.27 TB/s (latency convoy: vmcnt(0) drain/K-step)
//  - r1: dbuf 128x128 = 64KB LDS -> 2 blk/CU occupancy collapse, 1.93 TB/s. Confounded.
//  - r4: single-buf 128x64, 3 blk/CU (occ 39%), 2.1 TB/s -> BW flat vs occupancy,
//        so the drain itself is the limiter. This round: dbuf 128x64 (48KB, still 3 blk/CU)
//        isolates drain-removal at constant occupancy.
template <int BM, int BN, int WM, int WN, int RES, int OUT, int NTSW, int DBUF>
__global__ __launch_bounds__(256, (DBUF ? 3 : 4)) void gemm_bf16(const u16* __restrict__ A,
                                                    const u16* __restrict__ Bt,
                                                    const float* __restrict__ bias,
                                                    const void* __restrict__ res,
                                                    void* __restrict__ Cv,
                                                    int M, int N, int K) {
  constexpr int PM = BM / WM, PN = BN / WN;
  constexpr int FM = PM / 16, FN = PN / 16;
  constexpr int ASEG = BM / 32;
  constexpr int BSEG = BN / 32;
  constexpr int LPT = ASEG + BSEG;  // gload_lds instrs per wave per K-tile
  int bx, by;
  if (NTSW > 0) {
    int flat = blockIdx.x;
    int x = flat & 7, gidx = flat >> 3;
    bx = gidx % NTSW;
    int mg = gidx / NTSW;
    by = mg * 8 + x;
    if (by * BM >= M) return;
  } else {
    bx = blockIdx.x;
    by = blockIdx.y;
  }
  __shared__ u16 As[(1 + DBUF) * BM * 64];
  __shared__ u16 Bs[(1 + DBUF) * BN * 64];
  int tid = threadIdx.x;
  int w = tid >> 6, lane = tid & 63;
  int rw = w / WN, cw = w % WN;
  int m0 = by * BM, n0 = bx * BN;

  f32x4 acc[FM][FN];
#pragma unroll
  for (int i = 0; i < FM; ++i)
#pragma unroll
    for (int j = 0; j < FN; ++j) acc[i][j] = (f32x4){0.f, 0.f, 0.f, 0.f};

  int lr = lane >> 3;
  int lq = lane & 7;
  int qg = lq ^ lr;
  int l15 = lane & 15, quad = lane >> 4;

  int nk = K >> 6;

  auto stage = [&](int kk, int buf) {
#pragma unroll
    for (int i = 0; i < ASEG; ++i) {
      int s = w * ASEG + i;
      int row = s * 8 + lr;
      const u16* gp = A + (size_t)(m0 + row) * K + kk * 64 + qg * 8;
      __builtin_amdgcn_global_load_lds(
          (const __attribute__((address_space(1))) void*)gp,
          (__attribute__((address_space(3))) void*)&As[buf * (BM * 64) + s * 512], 16, 0, 0);
    }
#pragma unroll
    for (int i = 0; i < BSEG; ++i) {
      int s = w * BSEG + i;
      int row = s * 8 + lr;
      const u16* gp = Bt + (size_t)(n0 + row) * K + kk * 64 + qg * 8;
      __builtin_amdgcn_global_load_lds(
          (const __attribute__((address_space(1))) void*)gp,
          (__attribute__((address_space(3))) void*)&Bs[buf * (BN * 64) + s * 512], 16, 0, 0);
    }
  };

  auto compute = [&](const u16* Ab, const u16* Bb) {
#pragma unroll
    for (int s2 = 0; s2 < 2; ++s2) {
      bf16x8 af[FM], bfr[FN];
#pragma unroll
      for (int mt = 0; mt < FM; ++mt) {
        int rm = rw * PM + mt * 16 + l15;
        int ch = (s2 * 4 + quad) ^ (rm & 7);
        af[mt] = *(const bf16x8*)&Ab[rm * 64 + ch * 8];
      }
#pragma unroll
      for (int nt = 0; nt < FN; ++nt) {
        int rn = cw * PN + nt * 16 + l15;
        int ch = (s2 * 4 + quad) ^ (rn & 7);
        bfr[nt] = *(const bf16x8*)&Bb[rn * 64 + ch * 8];
      }
#pragma unroll
      for (int mt = 0; mt < FM; ++mt)
#pragma unroll
        for (int nt = 0; nt < FN; ++nt)
          acc[mt][nt] = __builtin_amdgcn_mfma_f32_16x16x32_bf16(af[mt], bfr[nt], acc[mt][nt], 0, 0, 0);
    }
  };

  if (DBUF == 0) {
    for (int t = 0; t < nk; ++t) {
      stage(t, 0);
      __syncthreads();
      compute(As, Bs);
      __syncthreads();
    }
  } else {
    // prologue
    stage(0, 0);
    for (int t = 0; t < nk; ++t) {
      int cur = t & 1;
      if (t + 1 < nk) {
        stage(t + 1, cur ^ 1);   // issue next tile; streams through compute + barriers
        waitcnt_vm<LPT>();       // wait ONLY tile-t's LPT loads (counted, not drain)
      } else {
        waitcnt_vm<0>();
      }
      __builtin_amdgcn_s_barrier();  // all waves' tile-t data visible in LDS
      compute(&As[cur * (BM * 64)], &Bs[cur * (BN * 64)]);
      if (t + 1 < nk) __builtin_amdgcn_s_barrier();  // buf[cur] free for stage(t+2)
    }
  }

#pragma unroll
  for (int mt = 0; mt < FM; ++mt) {
    int m = m0 + rw * PM + mt * 16 + quad * 4;
#pragma unroll
    for (int nt = 0; nt < FN; ++nt) {
      int n = n0 + cw * PN + nt * 16 + l15;
      float bsv = bias[n];
#pragma unroll
      for (int r = 0; r < 4; ++r) {
        size_t idx = (size_t)(m + r) * N + n;
        float v = acc[mt][nt][r] + bsv;
        if (RES == 1) v += ((const float*)res)[idx];
        if (RES == 2) v += bf2f(((const u16*)res)[idx]);
        if (OUT == 1) ((u16*)Cv)[idx] = f2bf(v);
        else ((float*)Cv)[idx] = v;
      }
    }
  }
}

// ---------------- merged weight prep (all transposes + concat) ----------------
#define PREP_B0 (DD * DD)            // Wv_t
#define PREP_B1 (2 * DD * DD)        // Wo_t
#define PREP_B2 (PREP_B1 + HID * DD) // W1_t (192x768)
#define PREP_B3 (PREP_B2 + HID * DD) // W2_t (768x192)
#define PREP_B4 (PREP_B3 + 128 * DD) // Wcat_t
__global__ __launch_bounds__(256) void prep_all(const float* __restrict__ Wv, const float* __restrict__ Wo,
                                                const float* __restrict__ W1, const float* __restrict__ W2,
                                                const float* __restrict__ Woff, const float* __restrict__ Wattn,
                                                const float* __restrict__ boff, const float* __restrict__ battn,
                                                u16* __restrict__ Wv_t, u16* __restrict__ Wo_t,
                                                u16* __restrict__ W1_t, u16* __restrict__ W2_t,
                                                u16* __restrict__ Wcat_t, float* __restrict__ bias_cat) {
  int idx = blockIdx.x * 256 + threadIdx.x;
  if (idx >= PREP_B4) return;
  if (idx < PREP_B0) {
    int n = idx / DD, k = idx - n * DD;
    Wv_t[idx] = f2bf(Wv[(size_t)k * DD + n]);
  } else if (idx < PREP_B1) {
    int l = idx - PREP_B0;
    int n = l / DD, k = l - n * DD;
    Wo_t[l] = f2bf(Wo[(size_t)k * DD + n]);
  } else if (idx < PREP_B2) {
    int l = idx - PREP_B1;                 // out: 192 x 768
    int n = l / DD, k = l - n * DD;
    W1_t[l] = f2bf(W1[(size_t)k * HID + n]);
  } else if (idx < PREP_B3) {
    int l = idx - PREP_B2;                 // out: 768 x 192
    int n = l / HID, k = l - n * HID;
    W2_t[l] = f2bf(W2[(size_t)k * DD + n]);
  } else {
    int l = idx - PREP_B3;                 // out: 128 x 768
    int n = l / DD, k = l - n * DD;
    float v = 0.f;
    if (n < 48) v = Woff[(size_t)k * 48 + n];
    else if (n < 72) v = Wattn[(size_t)k * 24 + (n - 48)];
    Wcat_t[l] = f2bf(v);
    if (l < 128) {
      float b = 0.f;
      if (l < 48) b = boff[l];
      else if (l < 72) b = battn[l - 48];
      bias_cat[l] = b;
    }
  }
}

// ---------------- fused softmax + bilinear sampling (192 threads = 3 waves) ----------------
// All 16 corner gathers per thread are loaded into an explicit statically-indexed
// array BEFORE accumulation, so the compiler keeps 16 loads in flight.
// Batch-XCD swizzle: row = (flat&1)*NN + (flat>>1) so each XCD serves mostly one
// batch's value table (3.5 MB < 4 MB L2).
__global__ __launch_bounds__(192) void sample_kernel(const u16* __restrict__ value,
                                                     const float* __restrict__ off,
                                                     const float* __restrict__ refp,
                                                     u16* __restrict__ s) {
  int flat = blockIdx.x;
  int b = flat & 1;
  size_t row = (size_t)b * NN + (flat >> 1);
  __shared__ int cidx[96];
  __shared__ float cw[96];
  int t = threadIdx.x;
  if (t < 24) {
    const float* o = off + row * 128;
    int hh = t >> 2, p = t & 3;
    float l0 = o[48 + hh * 4 + 0], l1 = o[48 + hh * 4 + 1];
    float l2 = o[48 + hh * 4 + 2], l3 = o[48 + hh * 4 + 3];
    float mx = fmaxf(fmaxf(l0, l1), fmaxf(l2, l3));
    float e0 = expf(l0 - mx), e1 = expf(l1 - mx), e2 = expf(l2 - mx), e3 = expf(l3 - mx);
    float sum = e0 + e1 + e2 + e3;
    float et = (p == 0) ? e0 : (p == 1) ? e1 : (p == 2) ? e2 : e3;
    float aw = et / sum;
    float x = refp[row * 2 + 0] * (float)WS - 0.5f + o[hh * 8 + p * 2 + 0];
    float y = refp[row * 2 + 1] * (float)HS - 0.5f + o[hh * 8 + p * 2 + 1];
    float xf = floorf(x), yf = floorf(y);
    int x0 = (int)xf, y0 = (int)yf;
    float wx = x - xf, wy = y - yf;
#pragma unroll
    for (int c = 0; c < 4; ++c) {
      int xi = x0 + (c & 1), yi = y0 + (c >> 1);
      float w = ((c & 1) ? wx : 1.f - wx) * ((c >> 1) ? wy : 1.f - wy);
      bool valid = (xi >= 0) && (xi < WS) && (yi >= 0) && (yi < HS);
      int xc = min(max(xi, 0), WS - 1), yc = min(max(yi, 0), HS - 1);
      cidx[t * 4 + c] = yc * WS + xc;
      cw[t * 4 + c] = valid ? w * aw : 0.f;
    }
  }
  __syncthreads();
  const u16* vb = value + (size_t)b * LL * DD;
  int c = t * 4;       // 192 threads x 4 channels = 768
  int h = c >> 7;      // head
  int base0 = h * 16;  // 16 (point,corner) slots for this head
  ushort4 v[16];
#pragma unroll
  for (int i = 0; i < 16; ++i)
    v[i] = *(const ushort4*)&vb[(size_t)cidx[base0 + i] * DD + c];
  float a0 = 0.f, a1 = 0.f, a2 = 0.f, a3 = 0.f;
#pragma unroll
  for (int i = 0; i < 16; ++i) {
    float w = cw[base0 + i];
    a0 += w * bf2f(v[i].x);
    a1 += w * bf2f(v[i].y);
    a2 += w * bf2f(v[i].z);
    a3 += w * bf2f(v[i].w);
  }
  ushort4 o4;
  o4.x = f2bf(a0); o4.y = f2bf(a1); o4.z = f2bf(a2); o4.w = f2bf(a3);
  *(ushort4*)&s[row * DD + c] = o4;
}

// ---------------- depthwise 3x3 (3 scales) + exact GELU, bf16 in/out ----------------
// one thread = one pixel x 4 contiguous channels (ushort4 loads/stores).
__global__ __launch_bounds__(256) void dwconv_gelu_kernel(const u16* __restrict__ h,
                                                          const float* __restrict__ w,
                                                          const float* __restrict__ bias,
                                                          u16* __restrict__ out) {
  size_t idx = (size_t)blockIdx.x * 256 + threadIdx.x;
  if (idx >= (size_t)BB * NN * (HID / 4)) return;
  int c4 = (int)(idx % (HID / 4));
  int c = c4 * 4;
  int rem = (int)(idx / (HID / 4));
  int nidx = rem % NN;
  int b = rem / NN;
  int hh, ww, base;
  if (nidx < 9216)       { hh = 96; ww = 96; base = 0; }
  else if (nidx < 11520) { hh = 48; ww = 48; base = 9216; }
  else                   { hh = 24; ww = 24; base = 11520; }
  int p = nidx - base;
  int y = p / ww, x = p % ww;
  const u16* hb = h + ((size_t)b * NN + base) * HID;
  float a0 = bias[c], a1 = bias[c + 1], a2 = bias[c + 2], a3 = bias[c + 3];
#pragma unroll
  for (int dy = -1; dy <= 1; ++dy) {
    int yy = y + dy;
    if (yy < 0 || yy >= hh) continue;
#pragma unroll
    for (int dx = -1; dx <= 1; ++dx) {
      int xx = x + dx;
      if (xx < 0 || xx >= ww) continue;
      ushort4 v = *(const ushort4*)&hb[((size_t)(yy * ww + xx)) * HID + c];
      int k = (dy + 1) * 3 + (dx + 1);
      a0 += bf2f(v.x) * w[(c + 0) * 9 + k];
      a1 += bf2f(v.y) * w[(c + 1) * 9 + k];
      a2 += bf2f(v.z) * w[(c + 2) * 9 + k];
      a3 += bf2f(v.w) * w[(c + 3) * 9 + k];
    }
  }
  ushort4 o;
  o.x = f2bf(0.5f * a0 * (1.f + erff(a0 * 0.70710678118654752f)));
  o.y = f2bf(0.5f * a1 * (1.f + erff(a1 * 0.70710678118654752f)));
  o.z = f2bf(0.5f * a2 * (1.f + erff(a2 * 0.70710678118654752f)));
  o.w = f2bf(0.5f * a3 * (1.f + erff(a3 * 0.70710678118654752f)));
  *(ushort4*)&out[(size_t)rem * HID + c] = o;
}

extern "C" void kernel_launch(void* const* d_in, const int* in_sizes, int n_in,
                              void* d_out, int out_size, void* d_ws, size_t ws_size,
                              hipStream_t stream) {
  const float* query = (const float*)d_in[0];
  const float* refp  = (const float*)d_in[1];
  const float* feat  = (const float*)d_in[2];
  const float* qn_g  = (const float*)d_in[7];
  const float* qn_b  = (const float*)d_in[8];
  const float* fn_g  = (const float*)d_in[9];
  const float* fn_b  = (const float*)d_in[10];
  const float* Wv    = (const float*)d_in[11];
  const float* bv    = (const float*)d_in[12];
  const float* Woff  = (const float*)d_in[13];
  const float* boff  = (const float*)d_in[14];
  const float* Wattn = (const float*)d_in[15];
  const float* battn = (const float*)d_in[16];
  const float* Wo    = (const float*)d_in[17];
  const float* bo    = (const float*)d_in[18];
  const float* ffn_g = (const float*)d_in[19];
  const float* ffn_b = (const float*)d_in[20];
  const float* W1    = (const float*)d_in[21];
  const float* b1    = (const float*)d_in[22];
  const float* dw_w  = (const float*)d_in[23];
  const float* dw_b  = (const float*)d_in[24];
  const float* W2    = (const float*)d_in[25];
  const float* b2    = (const float*)d_in[26];
  float* out = (float*)d_out;

  const int Mq = BB * NN;  // 24192
  const int Mf = BB * LL;  // 4608

  char* p = (char*)d_ws;
  auto alloc = [&](size_t bytes) { char* r = p; p += (bytes + 255) & ~(size_t)255; return r; };
  u16* qn_bf   = (u16*)alloc((size_t)Mq * DD * 2);   // reused for ln2
  u16* fn_bf   = (u16*)alloc((size_t)Mf * DD * 2);
  u16* val_bf  = (u16*)alloc((size_t)Mf * DD * 2);
  float* off   = (float*)alloc((size_t)Mq * 128 * 4);
  u16* s_bf    = (u16*)alloc((size_t)Mq * DD * 2);
  u16* q2_bf   = (u16*)alloc((size_t)Mq * DD * 2);
  u16* h_bf    = (u16*)alloc((size_t)Mq * HID * 2);
  u16* h2_bf   = (u16*)alloc((size_t)Mq * HID * 2);
  u16* Wv_t    = (u16*)alloc((size_t)DD * DD * 2);
  u16* Wo_t    = (u16*)alloc((size_t)DD * DD * 2);
  u16* W1_t    = (u16*)alloc((size_t)HID * DD * 2);
  u16* W2_t    = (u16*)alloc((size_t)DD * HID * 2);
  u16* Wcat_t  = (u16*)alloc((size_t)128 * DD * 2);
  float* bias_cat = (float*)alloc(128 * 4);

  // merged weight prep
  prep_all<<<(PREP_B4 + 255) / 256, 256, 0, stream>>>(Wv, Wo, W1, W2, Woff, Wattn, boff, battn,
                                                      Wv_t, Wo_t, W1_t, W2_t, Wcat_t, bias_cat);

  // LayerNorms (query + feat) -> bf16, one launch (192 thr = 3 waves, float4/ushort4 path)
  ln_dual_kernel<<<Mq + Mf, 192, 0, stream>>>(query, qn_g, qn_b, qn_bf, feat, fn_g, fn_b, fn_bf, Mq);

  // value = fn @ Wv + bv (bf16), 128x64 dbuf, XCD-swizzled (36 m-tiles, 12 n-tiles)
  gemm_bf16<128, 64, 2, 2, 0, 1, 12, 1><<<((Mf / 128 + 7) / 8) * 8 * 12, 256, 0, stream>>>(
      fn_bf, Wv_t, bv, nullptr, val_bf, Mf, DD, DD);

  // off|logits = qn @ Wcat + bias_cat (fp32), 64x64 dbuf (378 m-tiles, 2 n-tiles)
  gemm_bf16<64, 64, 2, 2, 0, 0, 2, 1><<<((Mq / 64 + 7) / 8) * 8 * 2, 256, 0, stream>>>(
      qn_bf, Wcat_t, bias_cat, nullptr, off, Mq, 128, DD);

  // fused softmax + bilinear sampling -> s (bf16), batch-XCD swizzled
  sample_kernel<<<Mq, 192, 0, stream>>>(val_bf, off, refp, s_bf);

  // q2 = query + s @ Wo + bo -> bf16, 128x64 dbuf, XCD-swizzled (189 m-tiles, 12 n-tiles)
  gemm_bf16<128, 64, 2, 2, 1, 1, 12, 1><<<((Mq / 128 + 7) / 8) * 8 * 12, 256, 0, stream>>>(
      s_bf, Wo_t, bo, query, q2_bf, Mq, DD, DD);

  // ln2 = LN(q2_bf) -> qn_bf (reuse)
  ln_kernel<u16><<<Mq, 192, 0, stream>>>(q2_bf, ffn_g, ffn_b, qn_bf);

  // h = ln2 @ W1 + b1 (bf16), 32x192 tiles single-buf (756 blocks)
  gemm_bf16<32, 192, 1, 4, 0, 1, 0, 0><<<dim3(1, Mq / 32), 256, 0, stream>>>(
      qn_bf, W1_t, b1, nullptr, h_bf, Mq, HID, DD);

  // depthwise conv + GELU (4 channels/thread)
  {
    size_t total = (size_t)BB * NN * (HID / 4);
    int blocks = (int)((total + 255) / 256);
    dwconv_gelu_kernel<<<blocks, 256, 0, stream>>>(h_bf, dw_w, dw_b, h2_bf);
  }

  // out = q2 + h2 @ W2 + b2 (fp32 final), 128x64 dbuf, XCD-swizzled
  gemm_bf16<128, 64, 2, 2, 2, 0, 12, 1><<<((Mq / 128 + 7) / 8) * 8 * 12, 256, 0, stream>>>(
      h2_bf, W2_t, b2, q2_bf, out, Mq, DD, HID);
}

// Round 7
// 413.566 us; speedup vs baseline: 1.0003x; 1.0003x over previous
//
#include <hip/hip_runtime.h>
#include <math.h>

// Problem constants (B=2, Hs=Ws=48, D=768, heads=6, P=4)
#define BB 2
#define NN 12096     // 21 * (48*48/4)
#define LL 2304      // 48*48
#define DD 768
#define HID 192
#define HS 48
#define WS 48

typedef unsigned short u16;
typedef unsigned int u32;
typedef __attribute__((ext_vector_type(8))) __bf16 bf16x8;
typedef __attribute__((ext_vector_type(8))) unsigned short u16x8;
typedef __attribute__((ext_vector_type(4))) float f32x4;

__device__ __forceinline__ u16 f2bf(float f) {
  u32 x = __builtin_bit_cast(u32, f);
  u32 r = (x + 0x7fffu + ((x >> 16) & 1u)) >> 16;  // RNE
  return (u16)r;
}
__device__ __forceinline__ float bf2f(u16 u) {
  u32 x = ((u32)u) << 16;
  return __builtin_bit_cast(float, x);
}

// ---------------- LayerNorm body (192 threads x 4 contiguous channels) ----------------
template <typename T>
__device__ __forceinline__ void ln_row4(const T* xr, const float* g, const float* bta, u16* yr, int t) {
  float v0, v1, v2, v3;
  if constexpr (sizeof(T) == 2) {
    ushort4 u = *(const ushort4*)(xr + 4 * t);
    v0 = bf2f(u.x); v1 = bf2f(u.y); v2 = bf2f(u.z); v3 = bf2f(u.w);
  } else {
    float4 f = *(const float4*)(xr + 4 * t);
    v0 = f.x; v1 = f.y; v2 = f.z; v3 = f.w;
  }
  float s = v0 + v1 + v2 + v3;
  float s2 = v0 * v0 + v1 * v1 + v2 * v2 + v3 * v3;
#pragma unroll
  for (int off = 32; off; off >>= 1) {
    s += __shfl_down(s, off, 64);
    s2 += __shfl_down(s2, off, 64);
  }
  __shared__ float red[6];
  __shared__ float mv[2];
  int wave = t >> 6, lane = t & 63;
  if (lane == 0) { red[wave] = s; red[3 + wave] = s2; }
  __syncthreads();
  if (t == 0) {
    float ts = red[0] + red[1] + red[2];
    float ts2 = red[3] + red[4] + red[5];
    float m = ts * (1.f / DD);
    float var = ts2 * (1.f / DD) - m * m;
    mv[0] = m;
    mv[1] = rsqrtf(var + 1e-6f);
  }
  __syncthreads();
  float m = mv[0], rs = mv[1];
  float4 gv = *(const float4*)(g + 4 * t);
  float4 bv = *(const float4*)(bta + 4 * t);
  ushort4 o;
  o.x = f2bf((v0 - m) * rs * gv.x + bv.x);
  o.y = f2bf((v1 - m) * rs * gv.y + bv.y);
  o.z = f2bf((v2 - m) * rs * gv.z + bv.z);
  o.w = f2bf((v3 - m) * rs * gv.w + bv.w);
  *(ushort4*)(yr + 4 * t) = o;
}

template <typename T>
__global__ __launch_bounds__(192) void ln_kernel(const T* __restrict__ x,
                                                 const float* __restrict__ g,
                                                 const float* __restrict__ bta,
                                                 u16* __restrict__ y) {
  size_t row = blockIdx.x;
  ln_row4<T>(x + row * DD, g, bta, y + row * DD, threadIdx.x);
}

// merged LN for query (Mq rows) and feat (Mf rows), both fp32
__global__ __launch_bounds__(192) void ln_dual_kernel(const float* __restrict__ xq,
                                                      const float* __restrict__ gq,
                                                      const float* __restrict__ bq,
                                                      u16* __restrict__ yq,
                                                      const float* __restrict__ xf,
                                                      const float* __restrict__ gf,
                                                      const float* __restrict__ bf_,
                                                      u16* __restrict__ yf,
                                                      int Mq) {
  size_t row = blockIdx.x;
  if (row < (size_t)Mq)
    ln_row4<float>(xq + row * DD, gq, bq, yq + row * DD, threadIdx.x);
  else {
    size_t r = row - Mq;
    ln_row4<float>(xf + r * DD, gf, bf_, yf + r * DD, threadIdx.x);
  }
}

// ---------------- bf16 MFMA GEMM ----------------
// C(MxN) = A(MxK)bf16 @ Bt(NxK)bf16 + bias (+res).
// RES: 0 none, 1 fp32, 2 bf16. OUT: 0 fp32, 1 bf16.
// NTSW: 0 -> plain 2D grid; else 1D grid with XCD-aware swizzle (NTSW = n-tile count).
// MINW: __launch_bounds__ min-waves/EU (2 for 128x128 -> VGPR 64 proven; 4 for smaller).
// REGIME NOTE (r6 post-mortem): the D=768 GEMMs here are COMPUTE/structure-bound,
// not BW-bound: q2 = 28.5 GFLOP / 47us = 604 TF, matching MfmaUtil 23%. Scheduling
// experiments (r1 dbuf-drain, r6 dbuf-counted-vmcnt, r4 small-tile occupancy) all
// land 2.0-2.27 TB/s: the 2-barrier K-loop structure's ~600-900 TF ceiling governs.
// Best measured: single-buf 128x128 (47.0us q2). Do not revisit LDS pipelining here.
template <int BM, int BN, int WM, int WN, int RES, int OUT, int NTSW, int MINW>
__global__ __launch_bounds__(256, MINW) void gemm_bf16(const u16* __restrict__ A,
                                                       const u16* __restrict__ Bt,
                                                       const float* __restrict__ bias,
                                                       const void* __restrict__ res,
                                                       void* __restrict__ Cv,
                                                       int M, int N, int K) {
  constexpr int PM = BM / WM, PN = BN / WN;
  constexpr int FM = PM / 16, FN = PN / 16;
  constexpr int ASEG = BM / 32;
  constexpr int BSEG = BN / 32;
  int bx, by;
  if (NTSW > 0) {
    int flat = blockIdx.x;
    int x = flat & 7, gidx = flat >> 3;
    bx = gidx % NTSW;
    int mg = gidx / NTSW;
    by = mg * 8 + x;
    if (by * BM >= M) return;
  } else {
    bx = blockIdx.x;
    by = blockIdx.y;
  }
  __shared__ u16 As[BM * 64];
  __shared__ u16 Bs[BN * 64];
  int tid = threadIdx.x;
  int w = tid >> 6, lane = tid & 63;
  int rw = w / WN, cw = w % WN;
  int m0 = by * BM, n0 = bx * BN;

  f32x4 acc[FM][FN];
#pragma unroll
  for (int i = 0; i < FM; ++i)
#pragma unroll
    for (int j = 0; j < FN; ++j) acc[i][j] = (f32x4){0.f, 0.f, 0.f, 0.f};

  int lr = lane >> 3;
  int lq = lane & 7;
  int qg = lq ^ lr;
  int l15 = lane & 15, quad = lane >> 4;

  for (int k0 = 0; k0 < K; k0 += 64) {
#pragma unroll
    for (int i = 0; i < ASEG; ++i) {
      int s = w * ASEG + i;
      int row = s * 8 + lr;
      const u16* gp = A + (size_t)(m0 + row) * K + k0 + qg * 8;
      __builtin_amdgcn_global_load_lds(
          (const __attribute__((address_space(1))) void*)gp,
          (__attribute__((address_space(3))) void*)&As[s * 512], 16, 0, 0);
    }
#pragma unroll
    for (int i = 0; i < BSEG; ++i) {
      int s = w * BSEG + i;
      int row = s * 8 + lr;
      const u16* gp = Bt + (size_t)(n0 + row) * K + k0 + qg * 8;
      __builtin_amdgcn_global_load_lds(
          (const __attribute__((address_space(1))) void*)gp,
          (__attribute__((address_space(3))) void*)&Bs[s * 512], 16, 0, 0);
    }
    __syncthreads();
#pragma unroll
    for (int s2 = 0; s2 < 2; ++s2) {
      bf16x8 af[FM], bfr[FN];
#pragma unroll
      for (int mt = 0; mt < FM; ++mt) {
        int rm = rw * PM + mt * 16 + l15;
        int ch = (s2 * 4 + quad) ^ (rm & 7);
        af[mt] = *(const bf16x8*)&As[rm * 64 + ch * 8];
      }
#pragma unroll
      for (int nt = 0; nt < FN; ++nt) {
        int rn = cw * PN + nt * 16 + l15;
        int ch = (s2 * 4 + quad) ^ (rn & 7);
        bfr[nt] = *(const bf16x8*)&Bs[rn * 64 + ch * 8];
      }
#pragma unroll
      for (int mt = 0; mt < FM; ++mt)
#pragma unroll
        for (int nt = 0; nt < FN; ++nt)
          acc[mt][nt] = __builtin_amdgcn_mfma_f32_16x16x32_bf16(af[mt], bfr[nt], acc[mt][nt], 0, 0, 0);
    }
    __syncthreads();
  }

#pragma unroll
  for (int mt = 0; mt < FM; ++mt) {
    int m = m0 + rw * PM + mt * 16 + quad * 4;
#pragma unroll
    for (int nt = 0; nt < FN; ++nt) {
      int n = n0 + cw * PN + nt * 16 + l15;
      float bsv = bias[n];
#pragma unroll
      for (int r = 0; r < 4; ++r) {
        size_t idx = (size_t)(m + r) * N + n;
        float v = acc[mt][nt][r] + bsv;
        if (RES == 1) v += ((const float*)res)[idx];
        if (RES == 2) v += bf2f(((const u16*)res)[idx]);
        if (OUT == 1) ((u16*)Cv)[idx] = f2bf(v);
        else ((float*)Cv)[idx] = v;
      }
    }
  }
}

// ---------------- merged weight prep (all transposes + concat) ----------------
#define PREP_B0 (DD * DD)            // Wv_t
#define PREP_B1 (2 * DD * DD)        // Wo_t
#define PREP_B2 (PREP_B1 + HID * DD) // W1_t (192x768)
#define PREP_B3 (PREP_B2 + HID * DD) // W2_t (768x192)
#define PREP_B4 (PREP_B3 + 128 * DD) // Wcat_t
__global__ __launch_bounds__(256) void prep_all(const float* __restrict__ Wv, const float* __restrict__ Wo,
                                                const float* __restrict__ W1, const float* __restrict__ W2,
                                                const float* __restrict__ Woff, const float* __restrict__ Wattn,
                                                const float* __restrict__ boff, const float* __restrict__ battn,
                                                u16* __restrict__ Wv_t, u16* __restrict__ Wo_t,
                                                u16* __restrict__ W1_t, u16* __restrict__ W2_t,
                                                u16* __restrict__ Wcat_t, float* __restrict__ bias_cat) {
  int idx = blockIdx.x * 256 + threadIdx.x;
  if (idx >= PREP_B4) return;
  if (idx < PREP_B0) {
    int n = idx / DD, k = idx - n * DD;
    Wv_t[idx] = f2bf(Wv[(size_t)k * DD + n]);
  } else if (idx < PREP_B1) {
    int l = idx - PREP_B0;
    int n = l / DD, k = l - n * DD;
    Wo_t[l] = f2bf(Wo[(size_t)k * DD + n]);
  } else if (idx < PREP_B2) {
    int l = idx - PREP_B1;                 // out: 192 x 768
    int n = l / DD, k = l - n * DD;
    W1_t[l] = f2bf(W1[(size_t)k * HID + n]);
  } else if (idx < PREP_B3) {
    int l = idx - PREP_B2;                 // out: 768 x 192
    int n = l / HID, k = l - n * HID;
    W2_t[l] = f2bf(W2[(size_t)k * DD + n]);
  } else {
    int l = idx - PREP_B3;                 // out: 128 x 768
    int n = l / DD, k = l - n * DD;
    float v = 0.f;
    if (n < 48) v = Woff[(size_t)k * 48 + n];
    else if (n < 72) v = Wattn[(size_t)k * 24 + (n - 48)];
    Wcat_t[l] = f2bf(v);
    if (l < 128) {
      float b = 0.f;
      if (l < 48) b = boff[l];
      else if (l < 72) b = battn[l - 48];
      bias_cat[l] = b;
    }
  }
}

// ---------------- fused softmax + bilinear sampling ----------------
// v3: 2 rows per block, 96 threads/row x 8 channels (u16x8 = 16B gathers).
// Halves gather instruction count vs v2 (ushort4) at constant bytes; 16 lanes x 16B
// per head-row stays coalesced. All 16 gathers in a statically-indexed array (ILP).
// Batch-XCD swizzle: b = flat&1 so each XCD serves mostly one batch's value table
// (3.5 MB < 4 MB L2).
__global__ __launch_bounds__(192) void sample_kernel(const u16* __restrict__ value,
                                                     const float* __restrict__ off,
                                                     const float* __restrict__ refp,
                                                     u16* __restrict__ s) {
  int flat = blockIdx.x;            // [0, BB*NN/2)
  int b = flat & 1;
  int pairi = flat >> 1;            // [0, NN/2)
  __shared__ int cidx[192];         // 2 rows x 96 slots
  __shared__ float cw[192];
  int t = threadIdx.x;
  if (t < 48) {
    int slr = t / 24;               // row-of-pair for softmax phase
    int u = t - slr * 24;           // unit: head*4 + point
    size_t row = (size_t)b * NN + (size_t)pairi * 2 + slr;
    const float* o = off + row * 128;
    int hh = u >> 2, p = u & 3;
    float l0 = o[48 + hh * 4 + 0], l1 = o[48 + hh * 4 + 1];
    float l2 = o[48 + hh * 4 + 2], l3 = o[48 + hh * 4 + 3];
    float mx = fmaxf(fmaxf(l0, l1), fmaxf(l2, l3));
    float e0 = expf(l0 - mx), e1 = expf(l1 - mx), e2 = expf(l2 - mx), e3 = expf(l3 - mx);
    float sum = e0 + e1 + e2 + e3;
    float et = (p == 0) ? e0 : (p == 1) ? e1 : (p == 2) ? e2 : e3;
    float aw = et / sum;
    float x = refp[row * 2 + 0] * (float)WS - 0.5f + o[hh * 8 + p * 2 + 0];
    float y = refp[row * 2 + 1] * (float)HS - 0.5f + o[hh * 8 + p * 2 + 1];
    float xf = floorf(x), yf = floorf(y);
    int x0 = (int)xf, y0 = (int)yf;
    float wx = x - xf, wy = y - yf;
#pragma unroll
    for (int c = 0; c < 4; ++c) {
      int xi = x0 + (c & 1), yi = y0 + (c >> 1);
      float w = ((c & 1) ? wx : 1.f - wx) * ((c >> 1) ? wy : 1.f - wy);
      bool valid = (xi >= 0) && (xi < WS) && (yi >= 0) && (yi < HS);
      int xc = min(max(xi, 0), WS - 1), yc = min(max(yi, 0), HS - 1);
      cidx[slr * 96 + u * 4 + c] = yc * WS + xc;
      cw[slr * 96 + u * 4 + c] = valid ? w * aw : 0.f;
    }
  }
  __syncthreads();
  int glr = t / 96;                 // row-of-pair for gather phase
  int ci = (t - glr * 96) * 8;      // channel base (8 channels/thread)
  size_t row = (size_t)b * NN + (size_t)pairi * 2 + glr;
  const u16* vb = value + (size_t)b * LL * DD;
  int h = ci >> 7;                  // head
  int base0 = glr * 96 + h * 16;    // 16 (point,corner) slots for this head+row
  u16x8 v[16];
#pragma unroll
  for (int i = 0; i < 16; ++i)
    v[i] = *(const u16x8*)&vb[(size_t)cidx[base0 + i] * DD + ci];
  float a0 = 0.f, a1 = 0.f, a2 = 0.f, a3 = 0.f;
  float a4 = 0.f, a5 = 0.f, a6 = 0.f, a7 = 0.f;
#pragma unroll
  for (int i = 0; i < 16; ++i) {
    float w = cw[base0 + i];
    a0 += w * bf2f(v[i][0]);
    a1 += w * bf2f(v[i][1]);
    a2 += w * bf2f(v[i][2]);
    a3 += w * bf2f(v[i][3]);
    a4 += w * bf2f(v[i][4]);
    a5 += w * bf2f(v[i][5]);
    a6 += w * bf2f(v[i][6]);
    a7 += w * bf2f(v[i][7]);
  }
  u16x8 o8;
  o8[0] = f2bf(a0); o8[1] = f2bf(a1); o8[2] = f2bf(a2); o8[3] = f2bf(a3);
  o8[4] = f2bf(a4); o8[5] = f2bf(a5); o8[6] = f2bf(a6); o8[7] = f2bf(a7);
  *(u16x8*)&s[row * DD + ci] = o8;
}

// ---------------- depthwise 3x3 (3 scales) + exact GELU, bf16 in/out ----------------
// one thread = one pixel x 4 contiguous channels (ushort4 loads/stores).
__global__ __launch_bounds__(256) void dwconv_gelu_kernel(const u16* __restrict__ h,
                                                          const float* __restrict__ w,
                                                          const float* __restrict__ bias,
                                                          u16* __restrict__ out) {
  size_t idx = (size_t)blockIdx.x * 256 + threadIdx.x;
  if (idx >= (size_t)BB * NN * (HID / 4)) return;
  int c4 = (int)(idx % (HID / 4));
  int c = c4 * 4;
  int rem = (int)(idx / (HID / 4));
  int nidx = rem % NN;
  int b = rem / NN;
  int hh, ww, base;
  if (nidx < 9216)       { hh = 96; ww = 96; base = 0; }
  else if (nidx < 11520) { hh = 48; ww = 48; base = 9216; }
  else                   { hh = 24; ww = 24; base = 11520; }
  int p = nidx - base;
  int y = p / ww, x = p % ww;
  const u16* hb = h + ((size_t)b * NN + base) * HID;
  float a0 = bias[c], a1 = bias[c + 1], a2 = bias[c + 2], a3 = bias[c + 3];
#pragma unroll
  for (int dy = -1; dy <= 1; ++dy) {
    int yy = y + dy;
    if (yy < 0 || yy >= hh) continue;
#pragma unroll
    for (int dx = -1; dx <= 1; ++dx) {
      int xx = x + dx;
      if (xx < 0 || xx >= ww) continue;
      ushort4 v = *(const ushort4*)&hb[((size_t)(yy * ww + xx)) * HID + c];
      int k = (dy + 1) * 3 + (dx + 1);
      a0 += bf2f(v.x) * w[(c + 0) * 9 + k];
      a1 += bf2f(v.y) * w[(c + 1) * 9 + k];
      a2 += bf2f(v.z) * w[(c + 2) * 9 + k];
      a3 += bf2f(v.w) * w[(c + 3) * 9 + k];
    }
  }
  ushort4 o;
  o.x = f2bf(0.5f * a0 * (1.f + erff(a0 * 0.70710678118654752f)));
  o.y = f2bf(0.5f * a1 * (1.f + erff(a1 * 0.70710678118654752f)));
  o.z = f2bf(0.5f * a2 * (1.f + erff(a2 * 0.70710678118654752f)));
  o.w = f2bf(0.5f * a3 * (1.f + erff(a3 * 0.70710678118654752f)));
  *(ushort4*)&out[(size_t)rem * HID + c] = o;
}

extern "C" void kernel_launch(void* const* d_in, const int* in_sizes, int n_in,
                              void* d_out, int out_size, void* d_ws, size_t ws_size,
                              hipStream_t stream) {
  const float* query = (const float*)d_in[0];
  const float* refp  = (const float*)d_in[1];
  const float* feat  = (const float*)d_in[2];
  const float* qn_g  = (const float*)d_in[7];
  const float* qn_b  = (const float*)d_in[8];
  const float* fn_g  = (const float*)d_in[9];
  const float* fn_b  = (const float*)d_in[10];
  const float* Wv    = (const float*)d_in[11];
  const float* bv    = (const float*)d_in[12];
  const float* Woff  = (const float*)d_in[13];
  const float* boff  = (const float*)d_in[14];
  const float* Wattn = (const float*)d_in[15];
  const float* battn = (const float*)d_in[16];
  const float* Wo    = (const float*)d_in[17];
  const float* bo    = (const float*)d_in[18];
  const float* ffn_g = (const float*)d_in[19];
  const float* ffn_b = (const float*)d_in[20];
  const float* W1    = (const float*)d_in[21];
  const float* b1    = (const float*)d_in[22];
  const float* dw_w  = (const float*)d_in[23];
  const float* dw_b  = (const float*)d_in[24];
  const float* W2    = (const float*)d_in[25];
  const float* b2    = (const float*)d_in[26];
  float* out = (float*)d_out;

  const int Mq = BB * NN;  // 24192
  const int Mf = BB * LL;  // 4608

  char* p = (char*)d_ws;
  auto alloc = [&](size_t bytes) { char* r = p; p += (bytes + 255) & ~(size_t)255; return r; };
  u16* qn_bf   = (u16*)alloc((size_t)Mq * DD * 2);   // reused for ln2
  u16* fn_bf   = (u16*)alloc((size_t)Mf * DD * 2);
  u16* val_bf  = (u16*)alloc((size_t)Mf * DD * 2);
  float* off   = (float*)alloc((size_t)Mq * 128 * 4);
  u16* s_bf    = (u16*)alloc((size_t)Mq * DD * 2);
  u16* q2_bf   = (u16*)alloc((size_t)Mq * DD * 2);
  u16* h_bf    = (u16*)alloc((size_t)Mq * HID * 2);
  u16* h2_bf   = (u16*)alloc((size_t)Mq * HID * 2);
  u16* Wv_t    = (u16*)alloc((size_t)DD * DD * 2);
  u16* Wo_t    = (u16*)alloc((size_t)DD * DD * 2);
  u16* W1_t    = (u16*)alloc((size_t)HID * DD * 2);
  u16* W2_t    = (u16*)alloc((size_t)DD * HID * 2);
  u16* Wcat_t  = (u16*)alloc((size_t)128 * DD * 2);
  float* bias_cat = (float*)alloc(128 * 4);

  // merged weight prep
  prep_all<<<(PREP_B4 + 255) / 256, 256, 0, stream>>>(Wv, Wo, W1, W2, Woff, Wattn, boff, battn,
                                                      Wv_t, Wo_t, W1_t, W2_t, Wcat_t, bias_cat);

  // LayerNorms (query + feat) -> bf16, one launch (192 thr = 3 waves, float4/ushort4 path)
  ln_dual_kernel<<<Mq + Mf, 192, 0, stream>>>(query, qn_g, qn_b, qn_bf, feat, fn_g, fn_b, fn_bf, Mq);

  // value = fn @ Wv + bv (bf16), 128x64 tiles, XCD-swizzled (36 m-tiles, 12 n-tiles)
  gemm_bf16<128, 64, 2, 2, 0, 1, 12, 4><<<((Mf / 128 + 7) / 8) * 8 * 12, 256, 0, stream>>>(
      fn_bf, Wv_t, bv, nullptr, val_bf, Mf, DD, DD);

  // off|logits = qn @ Wcat + bias_cat (fp32), 64x64 tiles (378 m-tiles, 2 n-tiles)
  gemm_bf16<64, 64, 2, 2, 0, 0, 2, 4><<<((Mq / 64 + 7) / 8) * 8 * 2, 256, 0, stream>>>(
      qn_bf, Wcat_t, bias_cat, nullptr, off, Mq, 128, DD);

  // fused softmax + bilinear sampling -> s (bf16), 2 rows/block, u16x8 gathers
  sample_kernel<<<Mq / 2, 192, 0, stream>>>(val_bf, off, refp, s_bf);

  // q2 = query + s @ Wo + bo -> bf16, 128x128 tiles, XCD-swizzled (189 m-tiles, 6 n-tiles)
  gemm_bf16<128, 128, 2, 2, 1, 1, 6, 2><<<((Mq / 128 + 7) / 8) * 8 * 6, 256, 0, stream>>>(
      s_bf, Wo_t, bo, query, q2_bf, Mq, DD, DD);

  // ln2 = LN(q2_bf) -> qn_bf (reuse)
  ln_kernel<u16><<<Mq, 192, 0, stream>>>(q2_bf, ffn_g, ffn_b, qn_bf);

  // h = ln2 @ W1 + b1 (bf16), 32x192 tiles (756 blocks)
  gemm_bf16<32, 192, 1, 4, 0, 1, 0, 4><<<dim3(1, Mq / 32), 256, 0, stream>>>(
      qn_bf, W1_t, b1, nullptr, h_bf, Mq, HID, DD);

  // depthwise conv + GELU (4 channels/thread)
  {
    size_t total = (size_t)BB * NN * (HID / 4);
    int blocks = (int)((total + 255) / 256);
    dwconv_gelu_kernel<<<blocks, 256, 0, stream>>>(h_bf, dw_w, dw_b, h2_bf);
  }

  // out = q2 + h2 @ W2 + b2 (fp32 final), 128x128 tiles, XCD-swizzled
  gemm_bf16<128, 128, 2, 2, 2, 0, 6, 2><<<((Mq / 128 + 7) / 8) * 8 * 6, 256, 0, stream>>>(
      h2_bf, W2_t, b2, q2_bf, out, Mq, DD, HID);
}

// Round 8
// 378.111 us; speedup vs baseline: 1.0941x; 1.0938x over previous
//
#include <hip/hip_runtime.h>
#include <math.h>

// Problem constants (B=2, Hs=Ws=48, D=768, heads=6, P=4)
#define BB 2
#define NN 12096     // 21 * (48*48/4)
#define LL 2304      // 48*48
#define DD 768
#define HID 192
#define HS 48
#define WS 48

typedef unsigned short u16;
typedef unsigned int u32;
typedef __attribute__((ext_vector_type(8))) __bf16 bf16x8;
typedef __attribute__((ext_vector_type(8))) unsigned short u16x8;
typedef __attribute__((ext_vector_type(4))) float f32x4;

__device__ __forceinline__ u16 f2bf(float f) {
  u32 x = __builtin_bit_cast(u32, f);
  u32 r = (x + 0x7fffu + ((x >> 16) & 1u)) >> 16;  // RNE
  return (u16)r;
}
__device__ __forceinline__ float bf2f(u16 u) {
  u32 x = ((u32)u) << 16;
  return __builtin_bit_cast(float, x);
}

// ---------------- LayerNorm body (192 threads x 4 contiguous channels) ----------------
template <typename T>
__device__ __forceinline__ void ln_row4(const T* xr, const float* g, const float* bta, u16* yr, int t) {
  float v0, v1, v2, v3;
  if constexpr (sizeof(T) == 2) {
    ushort4 u = *(const ushort4*)(xr + 4 * t);
    v0 = bf2f(u.x); v1 = bf2f(u.y); v2 = bf2f(u.z); v3 = bf2f(u.w);
  } else {
    float4 f = *(const float4*)(xr + 4 * t);
    v0 = f.x; v1 = f.y; v2 = f.z; v3 = f.w;
  }
  float s = v0 + v1 + v2 + v3;
  float s2 = v0 * v0 + v1 * v1 + v2 * v2 + v3 * v3;
#pragma unroll
  for (int off = 32; off; off >>= 1) {
    s += __shfl_down(s, off, 64);
    s2 += __shfl_down(s2, off, 64);
  }
  __shared__ float red[6];
  __shared__ float mv[2];
  int wave = t >> 6, lane = t & 63;
  if (lane == 0) { red[wave] = s; red[3 + wave] = s2; }
  __syncthreads();
  if (t == 0) {
    float ts = red[0] + red[1] + red[2];
    float ts2 = red[3] + red[4] + red[5];
    float m = ts * (1.f / DD);
    float var = ts2 * (1.f / DD) - m * m;
    mv[0] = m;
    mv[1] = rsqrtf(var + 1e-6f);
  }
  __syncthreads();
  float m = mv[0], rs = mv[1];
  float4 gv = *(const float4*)(g + 4 * t);
  float4 bv = *(const float4*)(bta + 4 * t);
  ushort4 o;
  o.x = f2bf((v0 - m) * rs * gv.x + bv.x);
  o.y = f2bf((v1 - m) * rs * gv.y + bv.y);
  o.z = f2bf((v2 - m) * rs * gv.z + bv.z);
  o.w = f2bf((v3 - m) * rs * gv.w + bv.w);
  *(ushort4*)(yr + 4 * t) = o;
}

template <typename T>
__global__ __launch_bounds__(192) void ln_kernel(const T* __restrict__ x,
                                                 const float* __restrict__ g,
                                                 const float* __restrict__ bta,
                                                 u16* __restrict__ y) {
  size_t row = blockIdx.x;
  ln_row4<T>(x + row * DD, g, bta, y + row * DD, threadIdx.x);
}

// merged LN for query (Mq rows) and feat (Mf rows), both fp32
__global__ __launch_bounds__(192) void ln_dual_kernel(const float* __restrict__ xq,
                                                      const float* __restrict__ gq,
                                                      const float* __restrict__ bq,
                                                      u16* __restrict__ yq,
                                                      const float* __restrict__ xf,
                                                      const float* __restrict__ gf,
                                                      const float* __restrict__ bf_,
                                                      u16* __restrict__ yf,
                                                      int Mq) {
  size_t row = blockIdx.x;
  if (row < (size_t)Mq)
    ln_row4<float>(xq + row * DD, gq, bq, yq + row * DD, threadIdx.x);
  else {
    size_t r = row - Mq;
    ln_row4<float>(xf + r * DD, gf, bf_, yf + r * DD, threadIdx.x);
  }
}

// ---------------- bf16 MFMA GEMM ----------------
// C(MxN) = A(MxK)bf16 @ Bt(NxK)bf16 + bias (+res).
// RES: 0 none, 1 fp32, 2 bf16. OUT: 0 fp32, 1 bf16.
// NTSW: 0 -> plain 2D grid; else 1D grid with XCD-aware swizzle (NTSW = n-tile count).
// MINW: __launch_bounds__ min-waves/EU (2 for 128x128 -> VGPR 64 proven; 4 for smaller).
// REGIME NOTE (r6 post-mortem): the D=768 GEMMs here are COMPUTE/structure-bound,
// not BW-bound: q2 = 28.5 GFLOP / 47us = 604 TF, matching MfmaUtil 23%. Scheduling
// experiments (r1 dbuf-drain, r6 dbuf-counted-vmcnt, r4 small-tile occupancy) all
// land 2.0-2.27 TB/s: the 2-barrier K-loop structure's ~600-900 TF ceiling governs.
// Best measured: single-buf 128x128 (47.0us q2). Do not revisit LDS pipelining here.
template <int BM, int BN, int WM, int WN, int RES, int OUT, int NTSW, int MINW>
__global__ __launch_bounds__(256, MINW) void gemm_bf16(const u16* __restrict__ A,
                                                       const u16* __restrict__ Bt,
                                                       const float* __restrict__ bias,
                                                       const void* __restrict__ res,
                                                       void* __restrict__ Cv,
                                                       int M, int N, int K) {
  constexpr int PM = BM / WM, PN = BN / WN;
  constexpr int FM = PM / 16, FN = PN / 16;
  constexpr int ASEG = BM / 32;
  constexpr int BSEG = BN / 32;
  int bx, by;
  if (NTSW > 0) {
    int flat = blockIdx.x;
    int x = flat & 7, gidx = flat >> 3;
    bx = gidx % NTSW;
    int mg = gidx / NTSW;
    by = mg * 8 + x;
    if (by * BM >= M) return;
  } else {
    bx = blockIdx.x;
    by = blockIdx.y;
  }
  __shared__ u16 As[BM * 64];
  __shared__ u16 Bs[BN * 64];
  int tid = threadIdx.x;
  int w = tid >> 6, lane = tid & 63;
  int rw = w / WN, cw = w % WN;
  int m0 = by * BM, n0 = bx * BN;

  f32x4 acc[FM][FN];
#pragma unroll
  for (int i = 0; i < FM; ++i)
#pragma unroll
    for (int j = 0; j < FN; ++j) acc[i][j] = (f32x4){0.f, 0.f, 0.f, 0.f};

  int lr = lane >> 3;
  int lq = lane & 7;
  int qg = lq ^ lr;
  int l15 = lane & 15, quad = lane >> 4;

  for (int k0 = 0; k0 < K; k0 += 64) {
#pragma unroll
    for (int i = 0; i < ASEG; ++i) {
      int s = w * ASEG + i;
      int row = s * 8 + lr;
      const u16* gp = A + (size_t)(m0 + row) * K + k0 + qg * 8;
      __builtin_amdgcn_global_load_lds(
          (const __attribute__((address_space(1))) void*)gp,
          (__attribute__((address_space(3))) void*)&As[s * 512], 16, 0, 0);
    }
#pragma unroll
    for (int i = 0; i < BSEG; ++i) {
      int s = w * BSEG + i;
      int row = s * 8 + lr;
      const u16* gp = Bt + (size_t)(n0 + row) * K + k0 + qg * 8;
      __builtin_amdgcn_global_load_lds(
          (const __attribute__((address_space(1))) void*)gp,
          (__attribute__((address_space(3))) void*)&Bs[s * 512], 16, 0, 0);
    }
    __syncthreads();
#pragma unroll
    for (int s2 = 0; s2 < 2; ++s2) {
      bf16x8 af[FM], bfr[FN];
#pragma unroll
      for (int mt = 0; mt < FM; ++mt) {
        int rm = rw * PM + mt * 16 + l15;
        int ch = (s2 * 4 + quad) ^ (rm & 7);
        af[mt] = *(const bf16x8*)&As[rm * 64 + ch * 8];
      }
#pragma unroll
      for (int nt = 0; nt < FN; ++nt) {
        int rn = cw * PN + nt * 16 + l15;
        int ch = (s2 * 4 + quad) ^ (rn & 7);
        bfr[nt] = *(const bf16x8*)&Bs[rn * 64 + ch * 8];
      }
#pragma unroll
      for (int mt = 0; mt < FM; ++mt)
#pragma unroll
        for (int nt = 0; nt < FN; ++nt)
          acc[mt][nt] = __builtin_amdgcn_mfma_f32_16x16x32_bf16(af[mt], bfr[nt], acc[mt][nt], 0, 0, 0);
    }
    __syncthreads();
  }

#pragma unroll
  for (int mt = 0; mt < FM; ++mt) {
    int m = m0 + rw * PM + mt * 16 + quad * 4;
#pragma unroll
    for (int nt = 0; nt < FN; ++nt) {
      int n = n0 + cw * PN + nt * 16 + l15;
      float bsv = bias[n];
#pragma unroll
      for (int r = 0; r < 4; ++r) {
        size_t idx = (size_t)(m + r) * N + n;
        float v = acc[mt][nt][r] + bsv;
        if (RES == 1) v += ((const float*)res)[idx];
        if (RES == 2) v += bf2f(((const u16*)res)[idx]);
        if (OUT == 1) ((u16*)Cv)[idx] = f2bf(v);
        else ((float*)Cv)[idx] = v;
      }
    }
  }
}

// ---------------- merged weight prep (all transposes + concat) ----------------
#define PREP_B0 (DD * DD)            // Wv_t
#define PREP_B1 (2 * DD * DD)        // Wo_t
#define PREP_B2 (PREP_B1 + HID * DD) // W1_t (192x768)
#define PREP_B3 (PREP_B2 + HID * DD) // W2_t (768x192)
#define PREP_B4 (PREP_B3 + 128 * DD) // Wcat_t
#define PREP_B5 (PREP_B4 + 9 * HID)  // dwt (9 x 192, transposed dw weights)
__global__ __launch_bounds__(256) void prep_all(const float* __restrict__ Wv, const float* __restrict__ Wo,
                                                const float* __restrict__ W1, const float* __restrict__ W2,
                                                const float* __restrict__ Woff, const float* __restrict__ Wattn,
                                                const float* __restrict__ boff, const float* __restrict__ battn,
                                                const float* __restrict__ dw_w,
                                                u16* __restrict__ Wv_t, u16* __restrict__ Wo_t,
                                                u16* __restrict__ W1_t, u16* __restrict__ W2_t,
                                                u16* __restrict__ Wcat_t, float* __restrict__ bias_cat,
                                                float* __restrict__ dwt) {
  int idx = blockIdx.x * 256 + threadIdx.x;
  if (idx >= PREP_B5) return;
  if (idx < PREP_B0) {
    int n = idx / DD, k = idx - n * DD;
    Wv_t[idx] = f2bf(Wv[(size_t)k * DD + n]);
  } else if (idx < PREP_B1) {
    int l = idx - PREP_B0;
    int n = l / DD, k = l - n * DD;
    Wo_t[l] = f2bf(Wo[(size_t)k * DD + n]);
  } else if (idx < PREP_B2) {
    int l = idx - PREP_B1;                 // out: 192 x 768
    int n = l / DD, k = l - n * DD;
    W1_t[l] = f2bf(W1[(size_t)k * HID + n]);
  } else if (idx < PREP_B3) {
    int l = idx - PREP_B2;                 // out: 768 x 192
    int n = l / HID, k = l - n * HID;
    W2_t[l] = f2bf(W2[(size_t)k * DD + n]);
  } else if (idx < PREP_B4) {
    int l = idx - PREP_B3;                 // out: 128 x 768
    int n = l / DD, k = l - n * DD;
    float v = 0.f;
    if (n < 48) v = Woff[(size_t)k * 48 + n];
    else if (n < 72) v = Wattn[(size_t)k * 24 + (n - 48)];
    Wcat_t[l] = f2bf(v);
    if (l < 128) {
      float b = 0.f;
      if (l < 48) b = boff[l];
      else if (l < 72) b = battn[l - 48];
      bias_cat[l] = b;
    }
  } else {
    int l = idx - PREP_B4;                 // out: 9 x 192 (tap-major)
    int k = l / HID, c = l - k * HID;
    dwt[l] = dw_w[(size_t)c * 9 + k];
  }
}

// ---------------- fused softmax + bilinear sampling ----------------
// v3: 2 rows per block, 96 threads/row x 8 channels (u16x8 = 16B gathers).
// All 16 gathers in a statically-indexed array (ILP). Batch-XCD swizzle: b = flat&1
// so each XCD serves mostly one batch's value table (3.5 MB < 4 MB L2).
__global__ __launch_bounds__(192) void sample_kernel(const u16* __restrict__ value,
                                                     const float* __restrict__ off,
                                                     const float* __restrict__ refp,
                                                     u16* __restrict__ s) {
  int flat = blockIdx.x;            // [0, BB*NN/2)
  int b = flat & 1;
  int pairi = flat >> 1;            // [0, NN/2)
  __shared__ int cidx[192];         // 2 rows x 96 slots
  __shared__ float cw[192];
  int t = threadIdx.x;
  if (t < 48) {
    int slr = t / 24;               // row-of-pair for softmax phase
    int u = t - slr * 24;           // unit: head*4 + point
    size_t row = (size_t)b * NN + (size_t)pairi * 2 + slr;
    const float* o = off + row * 128;
    int hh = u >> 2, p = u & 3;
    float l0 = o[48 + hh * 4 + 0], l1 = o[48 + hh * 4 + 1];
    float l2 = o[48 + hh * 4 + 2], l3 = o[48 + hh * 4 + 3];
    float mx = fmaxf(fmaxf(l0, l1), fmaxf(l2, l3));
    float e0 = expf(l0 - mx), e1 = expf(l1 - mx), e2 = expf(l2 - mx), e3 = expf(l3 - mx);
    float sum = e0 + e1 + e2 + e3;
    float et = (p == 0) ? e0 : (p == 1) ? e1 : (p == 2) ? e2 : e3;
    float aw = et / sum;
    float x = refp[row * 2 + 0] * (float)WS - 0.5f + o[hh * 8 + p * 2 + 0];
    float y = refp[row * 2 + 1] * (float)HS - 0.5f + o[hh * 8 + p * 2 + 1];
    float xf = floorf(x), yf = floorf(y);
    int x0 = (int)xf, y0 = (int)yf;
    float wx = x - xf, wy = y - yf;
#pragma unroll
    for (int c = 0; c < 4; ++c) {
      int xi = x0 + (c & 1), yi = y0 + (c >> 1);
      float w = ((c & 1) ? wx : 1.f - wx) * ((c >> 1) ? wy : 1.f - wy);
      bool valid = (xi >= 0) && (xi < WS) && (yi >= 0) && (yi < HS);
      int xc = min(max(xi, 0), WS - 1), yc = min(max(yi, 0), HS - 1);
      cidx[slr * 96 + u * 4 + c] = yc * WS + xc;
      cw[slr * 96 + u * 4 + c] = valid ? w * aw : 0.f;
    }
  }
  __syncthreads();
  int glr = t / 96;                 // row-of-pair for gather phase
  int ci = (t - glr * 96) * 8;      // channel base (8 channels/thread)
  size_t row = (size_t)b * NN + (size_t)pairi * 2 + glr;
  const u16* vb = value + (size_t)b * LL * DD;
  int h = ci >> 7;                  // head
  int base0 = glr * 96 + h * 16;    // 16 (point,corner) slots for this head+row
  u16x8 v[16];
#pragma unroll
  for (int i = 0; i < 16; ++i)
    v[i] = *(const u16x8*)&vb[(size_t)cidx[base0 + i] * DD + ci];
  float a0 = 0.f, a1 = 0.f, a2 = 0.f, a3 = 0.f;
  float a4 = 0.f, a5 = 0.f, a6 = 0.f, a7 = 0.f;
#pragma unroll
  for (int i = 0; i < 16; ++i) {
    float w = cw[base0 + i];
    a0 += w * bf2f(v[i][0]);
    a1 += w * bf2f(v[i][1]);
    a2 += w * bf2f(v[i][2]);
    a3 += w * bf2f(v[i][3]);
    a4 += w * bf2f(v[i][4]);
    a5 += w * bf2f(v[i][5]);
    a6 += w * bf2f(v[i][6]);
    a7 += w * bf2f(v[i][7]);
  }
  u16x8 o8;
  o8[0] = f2bf(a0); o8[1] = f2bf(a1); o8[2] = f2bf(a2); o8[3] = f2bf(a3);
  o8[4] = f2bf(a4); o8[5] = f2bf(a5); o8[6] = f2bf(a6); o8[7] = f2bf(a7);
  *(u16x8*)&s[row * DD + ci] = o8;
}

// ---------------- depthwise 3x3 (3 scales) + exact GELU, bf16 in/out ----------------
// v3 (r7 post-mortem): previous version had VGPR_Count=16 -> 9 neighbor loads + 36
// scalar weight loads serialized, latency-bound at 46.7us (585 GB/s, VALUBusy 14%).
// Fix: one thread = one pixel x 8 channels; all 9 neighbor u16x8 loads issued into a
// statically-indexed array (ILP); weights pre-transposed to [tap][channel] so weight
// fetch is 2x float4 per tap; boundary via clamped index + mask folded into weight.
__global__ __launch_bounds__(256) void dwconv_gelu_kernel(const u16* __restrict__ h,
                                                          const float* __restrict__ wt,
                                                          const float* __restrict__ bias,
                                                          u16* __restrict__ out) {
  size_t idx = (size_t)blockIdx.x * 256 + threadIdx.x;
  if (idx >= (size_t)BB * NN * (HID / 8)) return;
  int c8 = (int)(idx % (HID / 8));
  int c = c8 * 8;
  int rem = (int)(idx / (HID / 8));
  int nidx = rem % NN;
  int b = rem / NN;
  int hh, ww, base;
  if (nidx < 9216)       { hh = 96; ww = 96; base = 0; }
  else if (nidx < 11520) { hh = 48; ww = 48; base = 9216; }
  else                   { hh = 24; ww = 24; base = 11520; }
  int p = nidx - base;
  int y = p / ww, x = p % ww;
  const u16* hb = h + ((size_t)b * NN + base) * HID;

  int nbr[9];
  float msk[9];
#pragma unroll
  for (int dy = -1; dy <= 1; ++dy)
#pragma unroll
    for (int dx = -1; dx <= 1; ++dx) {
      int k = (dy + 1) * 3 + (dx + 1);
      int yy = y + dy, xx = x + dx;
      bool valid = (yy >= 0) && (yy < hh) && (xx >= 0) && (xx < ww);
      int yc = min(max(yy, 0), hh - 1), xc = min(max(xx, 0), ww - 1);
      nbr[k] = yc * ww + xc;
      msk[k] = valid ? 1.f : 0.f;
    }

  u16x8 v[9];
#pragma unroll
  for (int k = 0; k < 9; ++k)
    v[k] = *(const u16x8*)&hb[(size_t)nbr[k] * HID + c];

  float4 b0 = *(const float4*)&bias[c];
  float4 b1 = *(const float4*)&bias[c + 4];
  float a0 = b0.x, a1 = b0.y, a2 = b0.z, a3 = b0.w;
  float a4 = b1.x, a5 = b1.y, a6 = b1.z, a7 = b1.w;
#pragma unroll
  for (int k = 0; k < 9; ++k) {
    float4 w0 = *(const float4*)&wt[k * HID + c];
    float4 w1 = *(const float4*)&wt[k * HID + c + 4];
    float m = msk[k];
    a0 += m * w0.x * bf2f(v[k][0]);
    a1 += m * w0.y * bf2f(v[k][1]);
    a2 += m * w0.z * bf2f(v[k][2]);
    a3 += m * w0.w * bf2f(v[k][3]);
    a4 += m * w1.x * bf2f(v[k][4]);
    a5 += m * w1.y * bf2f(v[k][5]);
    a6 += m * w1.z * bf2f(v[k][6]);
    a7 += m * w1.w * bf2f(v[k][7]);
  }
  const float is2 = 0.70710678118654752f;
  u16x8 o8;
  o8[0] = f2bf(0.5f * a0 * (1.f + erff(a0 * is2)));
  o8[1] = f2bf(0.5f * a1 * (1.f + erff(a1 * is2)));
  o8[2] = f2bf(0.5f * a2 * (1.f + erff(a2 * is2)));
  o8[3] = f2bf(0.5f * a3 * (1.f + erff(a3 * is2)));
  o8[4] = f2bf(0.5f * a4 * (1.f + erff(a4 * is2)));
  o8[5] = f2bf(0.5f * a5 * (1.f + erff(a5 * is2)));
  o8[6] = f2bf(0.5f * a6 * (1.f + erff(a6 * is2)));
  o8[7] = f2bf(0.5f * a7 * (1.f + erff(a7 * is2)));
  *(u16x8*)&out[(size_t)rem * HID + c] = o8;
}

extern "C" void kernel_launch(void* const* d_in, const int* in_sizes, int n_in,
                              void* d_out, int out_size, void* d_ws, size_t ws_size,
                              hipStream_t stream) {
  const float* query = (const float*)d_in[0];
  const float* refp  = (const float*)d_in[1];
  const float* feat  = (const float*)d_in[2];
  const float* qn_g  = (const float*)d_in[7];
  const float* qn_b  = (const float*)d_in[8];
  const float* fn_g  = (const float*)d_in[9];
  const float* fn_b  = (const float*)d_in[10];
  const float* Wv    = (const float*)d_in[11];
  const float* bv    = (const float*)d_in[12];
  const float* Woff  = (const float*)d_in[13];
  const float* boff  = (const float*)d_in[14];
  const float* Wattn = (const float*)d_in[15];
  const float* battn = (const float*)d_in[16];
  const float* Wo    = (const float*)d_in[17];
  const float* bo    = (const float*)d_in[18];
  const float* ffn_g = (const float*)d_in[19];
  const float* ffn_b = (const float*)d_in[20];
  const float* W1    = (const float*)d_in[21];
  const float* b1    = (const float*)d_in[22];
  const float* dw_w  = (const float*)d_in[23];
  const float* dw_b  = (const float*)d_in[24];
  const float* W2    = (const float*)d_in[25];
  const float* b2    = (const float*)d_in[26];
  float* out = (float*)d_out;

  const int Mq = BB * NN;  // 24192
  const int Mf = BB * LL;  // 4608

  char* p = (char*)d_ws;
  auto alloc = [&](size_t bytes) { char* r = p; p += (bytes + 255) & ~(size_t)255; return r; };
  u16* qn_bf   = (u16*)alloc((size_t)Mq * DD * 2);   // reused for ln2
  u16* fn_bf   = (u16*)alloc((size_t)Mf * DD * 2);
  u16* val_bf  = (u16*)alloc((size_t)Mf * DD * 2);
  float* off   = (float*)alloc((size_t)Mq * 128 * 4);
  u16* s_bf    = (u16*)alloc((size_t)Mq * DD * 2);
  u16* q2_bf   = (u16*)alloc((size_t)Mq * DD * 2);
  u16* h_bf    = (u16*)alloc((size_t)Mq * HID * 2);
  u16* h2_bf   = (u16*)alloc((size_t)Mq * HID * 2);
  u16* Wv_t    = (u16*)alloc((size_t)DD * DD * 2);
  u16* Wo_t    = (u16*)alloc((size_t)DD * DD * 2);
  u16* W1_t    = (u16*)alloc((size_t)HID * DD * 2);
  u16* W2_t    = (u16*)alloc((size_t)DD * HID * 2);
  u16* Wcat_t  = (u16*)alloc((size_t)128 * DD * 2);
  float* bias_cat = (float*)alloc(128 * 4);
  float* dwt   = (float*)alloc((size_t)9 * HID * 4);

  // merged weight prep
  prep_all<<<(PREP_B5 + 255) / 256, 256, 0, stream>>>(Wv, Wo, W1, W2, Woff, Wattn, boff, battn, dw_w,
                                                      Wv_t, Wo_t, W1_t, W2_t, Wcat_t, bias_cat, dwt);

  // LayerNorms (query + feat) -> bf16, one launch (192 thr = 3 waves, float4/ushort4 path)
  ln_dual_kernel<<<Mq + Mf, 192, 0, stream>>>(query, qn_g, qn_b, qn_bf, feat, fn_g, fn_b, fn_bf, Mq);

  // value = fn @ Wv + bv (bf16), 128x64 tiles, XCD-swizzled (36 m-tiles, 12 n-tiles)
  gemm_bf16<128, 64, 2, 2, 0, 1, 12, 4><<<((Mf / 128 + 7) / 8) * 8 * 12, 256, 0, stream>>>(
      fn_bf, Wv_t, bv, nullptr, val_bf, Mf, DD, DD);

  // off|logits = qn @ Wcat + bias_cat (fp32), 64x64 tiles (378 m-tiles, 2 n-tiles)
  gemm_bf16<64, 64, 2, 2, 0, 0, 2, 4><<<((Mq / 64 + 7) / 8) * 8 * 2, 256, 0, stream>>>(
      qn_bf, Wcat_t, bias_cat, nullptr, off, Mq, 128, DD);

  // fused softmax + bilinear sampling -> s (bf16), 2 rows/block, u16x8 gathers
  sample_kernel<<<Mq / 2, 192, 0, stream>>>(val_bf, off, refp, s_bf);

  // q2 = query + s @ Wo + bo -> bf16, 128x128 tiles, XCD-swizzled (189 m-tiles, 6 n-tiles)
  gemm_bf16<128, 128, 2, 2, 1, 1, 6, 2><<<((Mq / 128 + 7) / 8) * 8 * 6, 256, 0, stream>>>(
      s_bf, Wo_t, bo, query, q2_bf, Mq, DD, DD);

  // ln2 = LN(q2_bf) -> qn_bf (reuse)
  ln_kernel<u16><<<Mq, 192, 0, stream>>>(q2_bf, ffn_g, ffn_b, qn_bf);

  // h = ln2 @ W1 + b1 (bf16), 32x192 tiles (756 blocks)
  gemm_bf16<32, 192, 1, 4, 0, 1, 0, 4><<<dim3(1, Mq / 32), 256, 0, stream>>>(
      qn_bf, W1_t, b1, nullptr, h_bf, Mq, HID, DD);

  // depthwise conv + GELU (8 channels/thread, ILP'd neighbor loads)
  {
    size_t total = (size_t)BB * NN * (HID / 8);
    int blocks = (int)((total + 255) / 256);
    dwconv_gelu_kernel<<<blocks, 256, 0, stream>>>(h_bf, dwt, dw_b, h2_bf);
  }

  // out = q2 + h2 @ W2 + b2 (fp32 final), 128x128 tiles, XCD-swizzled
  gemm_bf16<128, 128, 2, 2, 2, 0, 6, 2><<<((Mq / 128 + 7) / 8) * 8 * 6, 256, 0, stream>>>(
      h2_bf, W2_t, b2, q2_bf, out, Mq, DD, HID);
}

// Round 9
// 377.193 us; speedup vs baseline: 1.0968x; 1.0024x over previous
//
#include <hip/hip_runtime.h>
#include <math.h>

// Problem constants (B=2, Hs=Ws=48, D=768, heads=6, P=4)
#define BB 2
#define NN 12096     // 21 * (48*48/4)
#define LL 2304      // 48*48
#define DD 768
#define HID 192
#define HS 48
#define WS 48

typedef unsigned short u16;
typedef unsigned int u32;
typedef __attribute__((ext_vector_type(8))) __bf16 bf16x8;
typedef __attribute__((ext_vector_type(8))) unsigned short u16x8;
typedef __attribute__((ext_vector_type(4))) float f32x4;

__device__ __forceinline__ u16 f2bf(float f) {
  u32 x = __builtin_bit_cast(u32, f);
  u32 r = (x + 0x7fffu + ((x >> 16) & 1u)) >> 16;  // RNE
  return (u16)r;
}
__device__ __forceinline__ float bf2f(u16 u) {
  u32 x = ((u32)u) << 16;
  return __builtin_bit_cast(float, x);
}

// ---------------- LayerNorm (feat only now; 192 threads x 4 channels) ----------------
template <typename T>
__device__ __forceinline__ void ln_row4(const T* xr, const float* g, const float* bta, u16* yr, int t) {
  float v0, v1, v2, v3;
  if constexpr (sizeof(T) == 2) {
    ushort4 u = *(const ushort4*)(xr + 4 * t);
    v0 = bf2f(u.x); v1 = bf2f(u.y); v2 = bf2f(u.z); v3 = bf2f(u.w);
  } else {
    float4 f = *(const float4*)(xr + 4 * t);
    v0 = f.x; v1 = f.y; v2 = f.z; v3 = f.w;
  }
  float s = v0 + v1 + v2 + v3;
  float s2 = v0 * v0 + v1 * v1 + v2 * v2 + v3 * v3;
#pragma unroll
  for (int off = 32; off; off >>= 1) {
    s += __shfl_down(s, off, 64);
    s2 += __shfl_down(s2, off, 64);
  }
  __shared__ float red[6];
  __shared__ float mv[2];
  int wave = t >> 6, lane = t & 63;
  if (lane == 0) { red[wave] = s; red[3 + wave] = s2; }
  __syncthreads();
  if (t == 0) {
    float ts = red[0] + red[1] + red[2];
    float ts2 = red[3] + red[4] + red[5];
    float m = ts * (1.f / DD);
    float var = ts2 * (1.f / DD) - m * m;
    mv[0] = m;
    mv[1] = rsqrtf(var + 1e-6f);
  }
  __syncthreads();
  float m = mv[0], rs = mv[1];
  float4 gv = *(const float4*)(g + 4 * t);
  float4 bv = *(const float4*)(bta + 4 * t);
  ushort4 o;
  o.x = f2bf((v0 - m) * rs * gv.x + bv.x);
  o.y = f2bf((v1 - m) * rs * gv.y + bv.y);
  o.z = f2bf((v2 - m) * rs * gv.z + bv.z);
  o.w = f2bf((v3 - m) * rs * gv.w + bv.w);
  *(ushort4*)(yr + 4 * t) = o;
}

template <typename T>
__global__ __launch_bounds__(192) void ln_kernel(const T* __restrict__ x,
                                                 const float* __restrict__ g,
                                                 const float* __restrict__ bta,
                                                 u16* __restrict__ y) {
  size_t row = blockIdx.x;
  ln_row4<T>(x + row * DD, g, bta, y + row * DD, threadIdx.x);
}

// ---------------- bf16 MFMA GEMM ----------------
// C(MxN) = A(MxK)bf16 @ Bt(NxK)bf16 + bias (+res).
// RES: 0 none, 1 fp32, 2 bf16. OUT: 0 fp32, 1 bf16.
// NTSW: 0 -> plain 2D grid; else 1D grid with XCD-aware swizzle (NTSW = n-tile count).
// REGIME NOTE (r6): D=768 GEMMs are structure-bound (~610 TF, 2.27 TB/s) in this
// 2-barrier loop. r1/r4/r6 scheduling experiments all neutral-to-worse. Accepted.
template <int BM, int BN, int WM, int WN, int RES, int OUT, int NTSW, int MINW>
__global__ __launch_bounds__(256, MINW) void gemm_bf16(const u16* __restrict__ A,
                                                       const u16* __restrict__ Bt,
                                                       const float* __restrict__ bias,
                                                       const void* __restrict__ res,
                                                       void* __restrict__ Cv,
                                                       int M, int N, int K) {
  constexpr int PM = BM / WM, PN = BN / WN;
  constexpr int FM = PM / 16, FN = PN / 16;
  constexpr int ASEG = BM / 32;
  constexpr int BSEG = BN / 32;
  int bx, by;
  if (NTSW > 0) {
    int flat = blockIdx.x;
    int x = flat & 7, gidx = flat >> 3;
    bx = gidx % NTSW;
    int mg = gidx / NTSW;
    by = mg * 8 + x;
    if (by * BM >= M) return;
  } else {
    bx = blockIdx.x;
    by = blockIdx.y;
  }
  __shared__ u16 As[BM * 64];
  __shared__ u16 Bs[BN * 64];
  int tid = threadIdx.x;
  int w = tid >> 6, lane = tid & 63;
  int rw = w / WN, cw = w % WN;
  int m0 = by * BM, n0 = bx * BN;

  f32x4 acc[FM][FN];
#pragma unroll
  for (int i = 0; i < FM; ++i)
#pragma unroll
    for (int j = 0; j < FN; ++j) acc[i][j] = (f32x4){0.f, 0.f, 0.f, 0.f};

  int lr = lane >> 3;
  int lq = lane & 7;
  int qg = lq ^ lr;
  int l15 = lane & 15, quad = lane >> 4;

  for (int k0 = 0; k0 < K; k0 += 64) {
#pragma unroll
    for (int i = 0; i < ASEG; ++i) {
      int s = w * ASEG + i;
      int row = s * 8 + lr;
      const u16* gp = A + (size_t)(m0 + row) * K + k0 + qg * 8;
      __builtin_amdgcn_global_load_lds(
          (const __attribute__((address_space(1))) void*)gp,
          (__attribute__((address_space(3))) void*)&As[s * 512], 16, 0, 0);
    }
#pragma unroll
    for (int i = 0; i < BSEG; ++i) {
      int s = w * BSEG + i;
      int row = s * 8 + lr;
      const u16* gp = Bt + (size_t)(n0 + row) * K + k0 + qg * 8;
      __builtin_amdgcn_global_load_lds(
          (const __attribute__((address_space(1))) void*)gp,
          (__attribute__((address_space(3))) void*)&Bs[s * 512], 16, 0, 0);
    }
    __syncthreads();
#pragma unroll
    for (int s2 = 0; s2 < 2; ++s2) {
      bf16x8 af[FM], bfr[FN];
#pragma unroll
      for (int mt = 0; mt < FM; ++mt) {
        int rm = rw * PM + mt * 16 + l15;
        int ch = (s2 * 4 + quad) ^ (rm & 7);
        af[mt] = *(const bf16x8*)&As[rm * 64 + ch * 8];
      }
#pragma unroll
      for (int nt = 0; nt < FN; ++nt) {
        int rn = cw * PN + nt * 16 + l15;
        int ch = (s2 * 4 + quad) ^ (rn & 7);
        bfr[nt] = *(const bf16x8*)&Bs[rn * 64 + ch * 8];
      }
#pragma unroll
      for (int mt = 0; mt < FM; ++mt)
#pragma unroll
        for (int nt = 0; nt < FN; ++nt)
          acc[mt][nt] = __builtin_amdgcn_mfma_f32_16x16x32_bf16(af[mt], bfr[nt], acc[mt][nt], 0, 0, 0);
    }
    __syncthreads();
  }

#pragma unroll
  for (int mt = 0; mt < FM; ++mt) {
    int m = m0 + rw * PM + mt * 16 + quad * 4;
#pragma unroll
    for (int nt = 0; nt < FN; ++nt) {
      int n = n0 + cw * PN + nt * 16 + l15;
      float bsv = bias[n];
#pragma unroll
      for (int r = 0; r < 4; ++r) {
        size_t idx = (size_t)(m + r) * N + n;
        float v = acc[mt][nt][r] + bsv;
        if (RES == 1) v += ((const float*)res)[idx];
        if (RES == 2) v += bf2f(((const u16*)res)[idx]);
        if (OUT == 1) ((u16*)Cv)[idx] = f2bf(v);
        else ((float*)Cv)[idx] = v;
      }
    }
  }
}

// ---------------- fused LayerNorm + GEMM ----------------
// C(Mx BN-tile) = LN(A) @ Bt + bias. A raw (fp32 or bf16), K=768 fixed.
// BM=32 rows staged FULLY in LDS (12 K-steps x 32 x 64 bf16 = 48 KB), LN computed
// in-block: pass1 sums rows (8 thr/row, shfl_xor reduce), pass2 reloads (L2-hot) +
// normalizes + writes bf16 LDS in the GEMM XOR layout. K-loop then stages only B.
// Eliminates the qn_bf / ln2 intermediate round-trips (~148 MB total).
// WM=2, WN=2 -> wave tile 16 x BN/2. OUT: 0 fp32, 1 bf16.
template <typename T, int BN, int OUT>
__global__ __launch_bounds__(256, 2) void gemm_ln(const T* __restrict__ A,
                                                  const float* __restrict__ g,
                                                  const float* __restrict__ bta,
                                                  const u16* __restrict__ Bt,
                                                  const float* __restrict__ bias,
                                                  void* __restrict__ Cv,
                                                  int N) {
  constexpr int BM = 32;
  constexpr int PN = BN / 2;
  constexpr int FN = PN / 16;
  constexpr int BSEG = BN / 32;
  __shared__ u16 As[12 * BM * 64];   // 48 KB
  __shared__ u16 Bs[BN * 64];
  int tid = threadIdx.x;
  int w = tid >> 6, lane = tid & 63;
  int rw = w >> 1, cw = w & 1;
  int m0 = blockIdx.y * BM, n0 = blockIdx.x * BN;

  // ---- LN pass 1: per-row sums (8 threads per row, 12 slots of 8 values each)
  int r = tid >> 3;          // 0..31
  int q = tid & 7;
  const T* arow = A + (size_t)(m0 + r) * DD;
  float s = 0.f, s2 = 0.f;
#pragma unroll
  for (int i = 0; i < 12; ++i) {
    int slot = q + i * 8;                       // 0..95
    int j = slot >> 3, pp = slot & 7;
    int k = j * 64 + (pp ^ (r & 7)) * 8;
    if constexpr (sizeof(T) == 2) {
      u16x8 v = *(const u16x8*)(arow + k);
#pragma unroll
      for (int e = 0; e < 8; ++e) { float f = bf2f(v[e]); s += f; s2 += f * f; }
    } else {
      float4 f0 = *(const float4*)(arow + k);
      float4 f1 = *(const float4*)(arow + k + 4);
      s += f0.x + f0.y + f0.z + f0.w + f1.x + f1.y + f1.z + f1.w;
      s2 += f0.x*f0.x + f0.y*f0.y + f0.z*f0.z + f0.w*f0.w
          + f1.x*f1.x + f1.y*f1.y + f1.z*f1.z + f1.w*f1.w;
    }
  }
#pragma unroll
  for (int msk = 1; msk < 8; msk <<= 1) {
    s += __shfl_xor(s, msk, 64);
    s2 += __shfl_xor(s2, msk, 64);
  }
  float mean = s * (1.f / DD);
  float rs = rsqrtf(s2 * (1.f / DD) - mean * mean + 1e-6f);

  // ---- LN pass 2: reload (L2-hot), normalize, write bf16 LDS in GEMM layout
#pragma unroll
  for (int i = 0; i < 12; ++i) {
    int slot = q + i * 8;
    int j = slot >> 3, pp = slot & 7;
    int k = j * 64 + (pp ^ (r & 7)) * 8;
    float x[8];
    if constexpr (sizeof(T) == 2) {
      u16x8 v = *(const u16x8*)(arow + k);
#pragma unroll
      for (int e = 0; e < 8; ++e) x[e] = bf2f(v[e]);
    } else {
      float4 f0 = *(const float4*)(arow + k);
      float4 f1 = *(const float4*)(arow + k + 4);
      x[0]=f0.x; x[1]=f0.y; x[2]=f0.z; x[3]=f0.w;
      x[4]=f1.x; x[5]=f1.y; x[6]=f1.z; x[7]=f1.w;
    }
    float4 g0 = *(const float4*)(g + k);
    float4 g1 = *(const float4*)(g + k + 4);
    float4 b0 = *(const float4*)(bta + k);
    float4 b1 = *(const float4*)(bta + k + 4);
    float gg[8] = {g0.x,g0.y,g0.z,g0.w,g1.x,g1.y,g1.z,g1.w};
    float bb[8] = {b0.x,b0.y,b0.z,b0.w,b1.x,b1.y,b1.z,b1.w};
    u16x8 o;
#pragma unroll
    for (int e = 0; e < 8; ++e) o[e] = f2bf((x[e] - mean) * rs * gg[e] + bb[e]);
    *(u16x8*)&As[((size_t)j * BM + r) * 64 + pp * 8] = o;
  }
  __syncthreads();

  // ---- K-loop: stage B only; A fragments read from resident As
  f32x4 acc[FN];
#pragma unroll
  for (int j = 0; j < FN; ++j) acc[j] = (f32x4){0.f, 0.f, 0.f, 0.f};
  int lr = lane >> 3;
  int lq = lane & 7;
  int qg = lq ^ lr;
  int l15 = lane & 15, quad = lane >> 4;

  for (int j = 0; j < 12; ++j) {
#pragma unroll
    for (int i = 0; i < BSEG; ++i) {
      int sg = w * BSEG + i;
      int row = sg * 8 + lr;
      const u16* gp = Bt + (size_t)(n0 + row) * DD + j * 64 + qg * 8;
      __builtin_amdgcn_global_load_lds(
          (const __attribute__((address_space(1))) void*)gp,
          (__attribute__((address_space(3))) void*)&Bs[sg * 512], 16, 0, 0);
    }
    __syncthreads();
#pragma unroll
    for (int s2i = 0; s2i < 2; ++s2i) {
      int rm = rw * 16 + l15;
      int ch = (s2i * 4 + quad) ^ (rm & 7);
      bf16x8 af = *(const bf16x8*)&As[((size_t)j * BM + rm) * 64 + ch * 8];
      bf16x8 bfr[FN];
#pragma unroll
      for (int nt = 0; nt < FN; ++nt) {
        int rn = cw * PN + nt * 16 + l15;
        int chb = (s2i * 4 + quad) ^ (rn & 7);
        bfr[nt] = *(const bf16x8*)&Bs[rn * 64 + chb * 8];
      }
#pragma unroll
      for (int nt = 0; nt < FN; ++nt)
        acc[nt] = __builtin_amdgcn_mfma_f32_16x16x32_bf16(af, bfr[nt], acc[nt], 0, 0, 0);
    }
    __syncthreads();
  }

  // ---- epilogue
  int m = m0 + rw * 16 + quad * 4;
#pragma unroll
  for (int nt = 0; nt < FN; ++nt) {
    int n = n0 + cw * PN + nt * 16 + l15;
    float bsv = bias[n];
#pragma unroll
    for (int r4 = 0; r4 < 4; ++r4) {
      size_t idx = (size_t)(m + r4) * N + n;
      float v = acc[nt][r4] + bsv;
      if (OUT == 1) ((u16*)Cv)[idx] = f2bf(v);
      else ((float*)Cv)[idx] = v;
    }
  }
}

// ---------------- merged weight prep (all transposes + concat) ----------------
#define PREP_B0 (DD * DD)            // Wv_t
#define PREP_B1 (2 * DD * DD)        // Wo_t
#define PREP_B2 (PREP_B1 + HID * DD) // W1_t (192x768)
#define PREP_B3 (PREP_B2 + HID * DD) // W2_t (768x192)
#define PREP_B4 (PREP_B3 + 96 * DD)  // Wcat_t (96x768: 48 off + 24 attn + 24 pad)
#define PREP_B5 (PREP_B4 + 9 * HID)  // dwt (9 x 192, transposed dw weights)
__global__ __launch_bounds__(256) void prep_all(const float* __restrict__ Wv, const float* __restrict__ Wo,
                                                const float* __restrict__ W1, const float* __restrict__ W2,
                                                const float* __restrict__ Woff, const float* __restrict__ Wattn,
                                                const float* __restrict__ boff, const float* __restrict__ battn,
                                                const float* __restrict__ dw_w,
                                                u16* __restrict__ Wv_t, u16* __restrict__ Wo_t,
                                                u16* __restrict__ W1_t, u16* __restrict__ W2_t,
                                                u16* __restrict__ Wcat_t, float* __restrict__ bias_cat,
                                                float* __restrict__ dwt) {
  int idx = blockIdx.x * 256 + threadIdx.x;
  if (idx >= PREP_B5) return;
  if (idx < PREP_B0) {
    int n = idx / DD, k = idx - n * DD;
    Wv_t[idx] = f2bf(Wv[(size_t)k * DD + n]);
  } else if (idx < PREP_B1) {
    int l = idx - PREP_B0;
    int n = l / DD, k = l - n * DD;
    Wo_t[l] = f2bf(Wo[(size_t)k * DD + n]);
  } else if (idx < PREP_B2) {
    int l = idx - PREP_B1;                 // out: 192 x 768
    int n = l / DD, k = l - n * DD;
    W1_t[l] = f2bf(W1[(size_t)k * HID + n]);
  } else if (idx < PREP_B3) {
    int l = idx - PREP_B2;                 // out: 768 x 192
    int n = l / HID, k = l - n * HID;
    W2_t[l] = f2bf(W2[(size_t)k * DD + n]);
  } else if (idx < PREP_B4) {
    int l = idx - PREP_B3;                 // out: 96 x 768
    int n = l / DD, k = l - n * DD;
    float v = 0.f;
    if (n < 48) v = Woff[(size_t)k * 48 + n];
    else if (n < 72) v = Wattn[(size_t)k * 24 + (n - 48)];
    Wcat_t[l] = f2bf(v);
    if (l < 96) {
      float b = 0.f;
      if (l < 48) b = boff[l];
      else if (l < 72) b = battn[l - 48];
      bias_cat[l] = b;
    }
  } else {
    int l = idx - PREP_B4;                 // out: 9 x 192 (tap-major)
    int k = l / HID, c = l - k * HID;
    dwt[l] = dw_w[(size_t)c * 9 + k];
  }
}

// ---------------- fused softmax + bilinear sampling ----------------
// 2 rows per block, 96 threads/row x 8 channels (u16x8 = 16B gathers).
// off row stride is 96 (48 offset + 24 logits + pad).
__global__ __launch_bounds__(192) void sample_kernel(const u16* __restrict__ value,
                                                     const float* __restrict__ off,
                                                     const float* __restrict__ refp,
                                                     u16* __restrict__ s) {
  int flat = blockIdx.x;            // [0, BB*NN/2)
  int b = flat & 1;
  int pairi = flat >> 1;            // [0, NN/2)
  __shared__ int cidx[192];         // 2 rows x 96 slots
  __shared__ float cw[192];
  int t = threadIdx.x;
  if (t < 48) {
    int slr = t / 24;               // row-of-pair for softmax phase
    int u = t - slr * 24;           // unit: head*4 + point
    size_t row = (size_t)b * NN + (size_t)pairi * 2 + slr;
    const float* o = off + row * 96;
    int hh = u >> 2, p = u & 3;
    float l0 = o[48 + hh * 4 + 0], l1 = o[48 + hh * 4 + 1];
    float l2 = o[48 + hh * 4 + 2], l3 = o[48 + hh * 4 + 3];
    float mx = fmaxf(fmaxf(l0, l1), fmaxf(l2, l3));
    float e0 = expf(l0 - mx), e1 = expf(l1 - mx), e2 = expf(l2 - mx), e3 = expf(l3 - mx);
    float sum = e0 + e1 + e2 + e3;
    float et = (p == 0) ? e0 : (p == 1) ? e1 : (p == 2) ? e2 : e3;
    float aw = et / sum;
    float x = refp[row * 2 + 0] * (float)WS - 0.5f + o[hh * 8 + p * 2 + 0];
    float y = refp[row * 2 + 1] * (float)HS - 0.5f + o[hh * 8 + p * 2 + 1];
    float xf = floorf(x), yf = floorf(y);
    int x0 = (int)xf, y0 = (int)yf;
    float wx = x - xf, wy = y - yf;
#pragma unroll
    for (int c = 0; c < 4; ++c) {
      int xi = x0 + (c & 1), yi = y0 + (c >> 1);
      float w = ((c & 1) ? wx : 1.f - wx) * ((c >> 1) ? wy : 1.f - wy);
      bool valid = (xi >= 0) && (xi < WS) && (yi >= 0) && (yi < HS);
      int xc = min(max(xi, 0), WS - 1), yc = min(max(yi, 0), HS - 1);
      cidx[slr * 96 + u * 4 + c] = yc * WS + xc;
      cw[slr * 96 + u * 4 + c] = valid ? w * aw : 0.f;
    }
  }
  __syncthreads();
  int glr = t / 96;                 // row-of-pair for gather phase
  int ci = (t - glr * 96) * 8;      // channel base (8 channels/thread)
  size_t row = (size_t)b * NN + (size_t)pairi * 2 + glr;
  const u16* vb = value + (size_t)b * LL * DD;
  int h = ci >> 7;                  // head
  int base0 = glr * 96 + h * 16;    // 16 (point,corner) slots for this head+row
  u16x8 v[16];
#pragma unroll
  for (int i = 0; i < 16; ++i)
    v[i] = *(const u16x8*)&vb[(size_t)cidx[base0 + i] * DD + ci];
  float a0 = 0.f, a1 = 0.f, a2 = 0.f, a3 = 0.f;
  float a4 = 0.f, a5 = 0.f, a6 = 0.f, a7 = 0.f;
#pragma unroll
  for (int i = 0; i < 16; ++i) {
    float w = cw[base0 + i];
    a0 += w * bf2f(v[i][0]);
    a1 += w * bf2f(v[i][1]);
    a2 += w * bf2f(v[i][2]);
    a3 += w * bf2f(v[i][3]);
    a4 += w * bf2f(v[i][4]);
    a5 += w * bf2f(v[i][5]);
    a6 += w * bf2f(v[i][6]);
    a7 += w * bf2f(v[i][7]);
  }
  u16x8 o8;
  o8[0] = f2bf(a0); o8[1] = f2bf(a1); o8[2] = f2bf(a2); o8[3] = f2bf(a3);
  o8[4] = f2bf(a4); o8[5] = f2bf(a5); o8[6] = f2bf(a6); o8[7] = f2bf(a7);
  *(u16x8*)&s[row * DD + ci] = o8;
}

// ---------------- depthwise 3x3 (3 scales) + exact GELU, bf16 in/out ----------------
// one thread = one pixel x 8 channels; 9 neighbor u16x8 loads in a statically-indexed
// array (ILP); weights pre-transposed [tap][channel]; boundary mask folded into weight.
__global__ __launch_bounds__(256) void dwconv_gelu_kernel(const u16* __restrict__ h,
                                                          const float* __restrict__ wt,
                                                          const float* __restrict__ bias,
                                                          u16* __restrict__ out) {
  size_t idx = (size_t)blockIdx.x * 256 + threadIdx.x;
  if (idx >= (size_t)BB * NN * (HID / 8)) return;
  int c8 = (int)(idx % (HID / 8));
  int c = c8 * 8;
  int rem = (int)(idx / (HID / 8));
  int nidx = rem % NN;
  int b = rem / NN;
  int hh, ww, base;
  if (nidx < 9216)       { hh = 96; ww = 96; base = 0; }
  else if (nidx < 11520) { hh = 48; ww = 48; base = 9216; }
  else                   { hh = 24; ww = 24; base = 11520; }
  int p = nidx - base;
  int y = p / ww, x = p % ww;
  const u16* hb = h + ((size_t)b * NN + base) * HID;

  int nbr[9];
  float msk[9];
#pragma unroll
  for (int dy = -1; dy <= 1; ++dy)
#pragma unroll
    for (int dx = -1; dx <= 1; ++dx) {
      int k = (dy + 1) * 3 + (dx + 1);
      int yy = y + dy, xx = x + dx;
      bool valid = (yy >= 0) && (yy < hh) && (xx >= 0) && (xx < ww);
      int yc = min(max(yy, 0), hh - 1), xc = min(max(xx, 0), ww - 1);
      nbr[k] = yc * ww + xc;
      msk[k] = valid ? 1.f : 0.f;
    }

  u16x8 v[9];
#pragma unroll
  for (int k = 0; k < 9; ++k)
    v[k] = *(const u16x8*)&hb[(size_t)nbr[k] * HID + c];

  float4 b0 = *(const float4*)&bias[c];
  float4 b1 = *(const float4*)&bias[c + 4];
  float a0 = b0.x, a1 = b0.y, a2 = b0.z, a3 = b0.w;
  float a4 = b1.x, a5 = b1.y, a6 = b1.z, a7 = b1.w;
#pragma unroll
  for (int k = 0; k < 9; ++k) {
    float4 w0 = *(const float4*)&wt[k * HID + c];
    float4 w1 = *(const float4*)&wt[k * HID + c + 4];
    float m = msk[k];
    a0 += m * w0.x * bf2f(v[k][0]);
    a1 += m * w0.y * bf2f(v[k][1]);
    a2 += m * w0.z * bf2f(v[k][2]);
    a3 += m * w0.w * bf2f(v[k][3]);
    a4 += m * w1.x * bf2f(v[k][4]);
    a5 += m * w1.y * bf2f(v[k][5]);
    a6 += m * w1.z * bf2f(v[k][6]);
    a7 += m * w1.w * bf2f(v[k][7]);
  }
  const float is2 = 0.70710678118654752f;
  u16x8 o8;
  o8[0] = f2bf(0.5f * a0 * (1.f + erff(a0 * is2)));
  o8[1] = f2bf(0.5f * a1 * (1.f + erff(a1 * is2)));
  o8[2] = f2bf(0.5f * a2 * (1.f + erff(a2 * is2)));
  o8[3] = f2bf(0.5f * a3 * (1.f + erff(a3 * is2)));
  o8[4] = f2bf(0.5f * a4 * (1.f + erff(a4 * is2)));
  o8[5] = f2bf(0.5f * a5 * (1.f + erff(a5 * is2)));
  o8[6] = f2bf(0.5f * a6 * (1.f + erff(a6 * is2)));
  o8[7] = f2bf(0.5f * a7 * (1.f + erff(a7 * is2)));
  *(u16x8*)&out[(size_t)rem * HID + c] = o8;
}

extern "C" void kernel_launch(void* const* d_in, const int* in_sizes, int n_in,
                              void* d_out, int out_size, void* d_ws, size_t ws_size,
                              hipStream_t stream) {
  const float* query = (const float*)d_in[0];
  const float* refp  = (const float*)d_in[1];
  const float* feat  = (const float*)d_in[2];
  const float* qn_g  = (const float*)d_in[7];
  const float* qn_b  = (const float*)d_in[8];
  const float* fn_g  = (const float*)d_in[9];
  const float* fn_b  = (const float*)d_in[10];
  const float* Wv    = (const float*)d_in[11];
  const float* bv    = (const float*)d_in[12];
  const float* Woff  = (const float*)d_in[13];
  const float* boff  = (const float*)d_in[14];
  const float* Wattn = (const float*)d_in[15];
  const float* battn = (const float*)d_in[16];
  const float* Wo    = (const float*)d_in[17];
  const float* bo    = (const float*)d_in[18];
  const float* ffn_g = (const float*)d_in[19];
  const float* ffn_b = (const float*)d_in[20];
  const float* W1    = (const float*)d_in[21];
  const float* b1    = (const float*)d_in[22];
  const float* dw_w  = (const float*)d_in[23];
  const float* dw_b  = (const float*)d_in[24];
  const float* W2    = (const float*)d_in[25];
  const float* b2    = (const float*)d_in[26];
  float* out = (float*)d_out;

  const int Mq = BB * NN;  // 24192
  const int Mf = BB * LL;  // 4608

  char* p = (char*)d_ws;
  auto alloc = [&](size_t bytes) { char* r = p; p += (bytes + 255) & ~(size_t)255; return r; };
  u16* fn_bf   = (u16*)alloc((size_t)Mf * DD * 2);
  u16* val_bf  = (u16*)alloc((size_t)Mf * DD * 2);
  float* off   = (float*)alloc((size_t)Mq * 96 * 4);
  u16* s_bf    = (u16*)alloc((size_t)Mq * DD * 2);
  u16* q2_bf   = (u16*)alloc((size_t)Mq * DD * 2);
  u16* h_bf    = (u16*)alloc((size_t)Mq * HID * 2);
  u16* h2_bf   = (u16*)alloc((size_t)Mq * HID * 2);
  u16* Wv_t    = (u16*)alloc((size_t)DD * DD * 2);
  u16* Wo_t    = (u16*)alloc((size_t)DD * DD * 2);
  u16* W1_t    = (u16*)alloc((size_t)HID * DD * 2);
  u16* W2_t    = (u16*)alloc((size_t)DD * HID * 2);
  u16* Wcat_t  = (u16*)alloc((size_t)96 * DD * 2);
  float* bias_cat = (float*)alloc(96 * 4);
  float* dwt   = (float*)alloc((size_t)9 * HID * 4);

  // merged weight prep
  prep_all<<<(PREP_B5 + 255) / 256, 256, 0, stream>>>(Wv, Wo, W1, W2, Woff, Wattn, boff, battn, dw_w,
                                                      Wv_t, Wo_t, W1_t, W2_t, Wcat_t, bias_cat, dwt);

  // LN(feat) -> bf16 (query LN is fused into the off-GEMM)
  ln_kernel<float><<<Mf, 192, 0, stream>>>(feat, fn_g, fn_b, fn_bf);

  // value = fn @ Wv + bv (bf16), 128x64 tiles, XCD-swizzled (36 m-tiles, 12 n-tiles)
  gemm_bf16<128, 64, 2, 2, 0, 1, 12, 4><<<((Mf / 128 + 7) / 8) * 8 * 12, 256, 0, stream>>>(
      fn_bf, Wv_t, bv, nullptr, val_bf, Mf, DD, DD);

  // off|logits = LN(query) @ Wcat + bias_cat (fp32, N=96), fused LN-GEMM
  gemm_ln<float, 96, 0><<<dim3(1, Mq / 32), 256, 0, stream>>>(
      query, qn_g, qn_b, Wcat_t, bias_cat, off, 96);

  // fused softmax + bilinear sampling -> s (bf16), 2 rows/block, u16x8 gathers
  sample_kernel<<<Mq / 2, 192, 0, stream>>>(val_bf, off, refp, s_bf);

  // q2 = query + s @ Wo + bo -> bf16, 128x128 tiles, XCD-swizzled (189 m-tiles, 6 n-tiles)
  gemm_bf16<128, 128, 2, 2, 1, 1, 6, 2><<<((Mq / 128 + 7) / 8) * 8 * 6, 256, 0, stream>>>(
      s_bf, Wo_t, bo, query, q2_bf, Mq, DD, DD);

  // h = LN(q2) @ W1 + b1 (bf16), fused LN-GEMM (2 n-tiles of 96)
  gemm_ln<u16, 96, 1><<<dim3(2, Mq / 32), 256, 0, stream>>>(
      q2_bf, ffn_g, ffn_b, W1_t, b1, h_bf, HID);

  // depthwise conv + GELU (8 channels/thread, ILP'd neighbor loads)
  {
    size_t total = (size_t)BB * NN * (HID / 8);
    int blocks = (int)((total + 255) / 256);
    dwconv_gelu_kernel<<<blocks, 256, 0, stream>>>(h_bf, dwt, dw_b, h2_bf);
  }

  // out = q2 + h2 @ W2 + b2 (fp32 final), 128x128 tiles, XCD-swizzled
  gemm_bf16<128, 128, 2, 2, 2, 0, 6, 2><<<((Mq / 128 + 7) / 8) * 8 * 6, 256, 0, stream>>>(
      h2_bf, W2_t, b2, q2_bf, out, Mq, DD, HID);
}